// Round 1
// baseline (11847.085 us; speedup 1.0000x reference)
//
#include <hip/hip_runtime.h>
#include <stdint.h>

#define T_DIM 512
#define B_DIM 64
#define E_DIM 1024
#define H_DIM 1024
#define G_DIM 4096  // 4*H, packed as p = j*4 + gate

typedef short bf16x8 __attribute__((ext_vector_type(8)));
typedef float f32x4 __attribute__((ext_vector_type(4)));

__device__ __forceinline__ unsigned short f2b(float f){
  union{float f; unsigned u;} v; v.f = f;
  unsigned r = (v.u + 0x7FFFu + ((v.u >> 16) & 1u)) >> 16;  // RNE
  return (unsigned short)r;
}

// ---------------- prep kernels ----------------

// Pack W (4 gates, each [H, E+H] fp32) into bf16, gate-interleaved rows:
// packed row p = j*4+g maps to gate g, hidden unit j.
// WxB[p][k] = W_g[j][k] (k<1024), WhB[p][k] = W_g[j][1024+k]. biasP[p] = b_g[j].
__global__ void pack_weights(const float* __restrict__ Wf, const float* __restrict__ Wi,
                             const float* __restrict__ Wo, const float* __restrict__ Wc,
                             const float* __restrict__ bfv, const float* __restrict__ biv,
                             const float* __restrict__ bov, const float* __restrict__ bcv,
                             unsigned short* __restrict__ WxB, unsigned short* __restrict__ WhB,
                             float* __restrict__ biasP){
  int p = blockIdx.x;            // 0..4095
  int j = p >> 2, g = p & 3;
  const float* W    = (g==0)?Wf:(g==1)?Wi:(g==2)?Wo:Wc;
  const float* bsrc = (g==0)?bfv:(g==1)?biv:(g==2)?bov:bcv;
  const float* wrow = W + (size_t)j * 2048;
  int t = threadIdx.x;           // 256 threads, 4 k each
  float4 x = *(const float4*)(wrow + 4*t);
  float4 h = *(const float4*)(wrow + 1024 + 4*t);
  ushort4 xo = make_ushort4(f2b(x.x), f2b(x.y), f2b(x.z), f2b(x.w));
  ushort4 ho = make_ushort4(f2b(h.x), f2b(h.y), f2b(h.z), f2b(h.w));
  *(ushort4*)&WxB[(size_t)p*1024 + 4*t] = xo;
  *(ushort4*)&WhB[(size_t)p*1024 + 4*t] = ho;
  if (t == 0) biasP[p] = bsrc[j];
}

__global__ void conv_emb(const float* __restrict__ emb, unsigned short* __restrict__ embB){
  const size_t n4 = (size_t)T_DIM * B_DIM * E_DIM / 4;   // 8388608
  for (size_t i = (size_t)blockIdx.x * blockDim.x + threadIdx.x; i < n4;
       i += (size_t)gridDim.x * blockDim.x){
    float4 v = ((const float4*)emb)[i];
    ((ushort4*)embB)[i] = make_ushort4(f2b(v.x), f2b(v.y), f2b(v.z), f2b(v.w));
  }
}

__global__ void zero_state(unsigned short* __restrict__ h0, unsigned short* __restrict__ h1,
                           float* __restrict__ c){
  int i = blockIdx.x * blockDim.x + threadIdx.x;  // 65536 threads exactly
  h0[i] = 0; h1[i] = 0; c[i] = 0.f;
}

// ---------------- big GEMM: xg = embB @ WxB^T ----------------
// A: [32768][1024] bf16 row-major. B: [4096][1024] bf16 row-major (row = output col).
// C: [32768][4096] fp32. Tile 128x128, BK=32, 4 waves (2x2), each wave 64x64.
__launch_bounds__(256)
__global__ void gemm_xg(const unsigned short* __restrict__ A,
                        const unsigned short* __restrict__ B,
                        float* __restrict__ C){
  __shared__ unsigned short Al[128*32];
  __shared__ unsigned short Bl[128*32];
  int m0 = blockIdx.x * 128, n0 = blockIdx.y * 128;
  int tid = threadIdx.x, lane = tid & 63, wid = tid >> 6;
  int mblk = (wid >> 1) * 64, nblk = (wid & 1) * 64;
  int rl = lane & 15, kg = lane >> 4;
  f32x4 acc[4][4] = {};

  for (int kk = 0; kk < 1024; kk += 32){
    // stage 128 rows x 32 k of each operand; chunk = 16B (8 bf16)
    {
      int c0 = tid, c1 = tid + 256;
      int r = c0 >> 2, g = c0 & 3, s = g ^ ((r >> 1) & 3);
      *(uint4*)&Al[r*32 + s*8] = *(const uint4*)&A[(size_t)(m0 + r)*1024 + kk + g*8];
      *(uint4*)&Bl[r*32 + s*8] = *(const uint4*)&B[(size_t)(n0 + r)*1024 + kk + g*8];
      r = c1 >> 2; g = c1 & 3; s = g ^ ((r >> 1) & 3);
      *(uint4*)&Al[r*32 + s*8] = *(const uint4*)&A[(size_t)(m0 + r)*1024 + kk + g*8];
      *(uint4*)&Bl[r*32 + s*8] = *(const uint4*)&B[(size_t)(n0 + r)*1024 + kk + g*8];
    }
    __syncthreads();
    bf16x8 a[4], b[4];
    #pragma unroll
    for (int mf = 0; mf < 4; ++mf){
      int r = mblk + mf*16 + rl;
      a[mf] = *(const bf16x8*)&Al[r*32 + (kg ^ ((r >> 1) & 3))*8];
    }
    #pragma unroll
    for (int nf = 0; nf < 4; ++nf){
      int r = nblk + nf*16 + rl;
      b[nf] = *(const bf16x8*)&Bl[r*32 + (kg ^ ((r >> 1) & 3))*8];
    }
    #pragma unroll
    for (int mf = 0; mf < 4; ++mf)
      #pragma unroll
      for (int nf = 0; nf < 4; ++nf)
        acc[mf][nf] = __builtin_amdgcn_mfma_f32_16x16x32_bf16(a[mf], b[nf], acc[mf][nf], 0, 0, 0);
    __syncthreads();
  }

  // C/D layout (m89-verified): col = lane&15, row = (lane>>4)*4 + reg
  int rq = kg * 4;
  #pragma unroll
  for (int mf = 0; mf < 4; ++mf)
    #pragma unroll
    for (int nf = 0; nf < 4; ++nf){
      int col = n0 + nblk + nf*16 + rl;
      #pragma unroll
      for (int r = 0; r < 4; ++r){
        int row = m0 + mblk + mf*16 + rq + r;
        C[(size_t)row * G_DIM + col] = acc[mf][nf][r];
      }
    }
}

// ---------------- recurrent step ----------------
// Grid 256 blocks x 256 threads. Block blk owns packed cols [blk*16, blk*16+16)
// = hidden units j in [blk*4, blk*4+4) x 4 gates. 4 waves, wave w = batch rows [16w,16w+16).
// g = (xg_t or emb_t@WxB^T) + h_in@WhB^T ; then gates -> c,h update.
__device__ __forceinline__ bf16x8 cvt_f8(const float* p){
  float4 u = *(const float4*)p;
  float4 v = *(const float4*)(p + 4);
  bf16x8 r;
  r[0] = (short)f2b(u.x); r[1] = (short)f2b(u.y); r[2] = (short)f2b(u.z); r[3] = (short)f2b(u.w);
  r[4] = (short)f2b(v.x); r[5] = (short)f2b(v.y); r[6] = (short)f2b(v.z); r[7] = (short)f2b(v.w);
  return r;
}

__launch_bounds__(256)
__global__ void lstm_step(const unsigned short* __restrict__ WhB,
                          const unsigned short* __restrict__ WxB,
                          const float* __restrict__ xg_t,      // non-null: precomputed path
                          const float* __restrict__ emb_t,     // non-null: fused path
                          const unsigned short* __restrict__ h_in,
                          unsigned short* __restrict__ h_out,
                          float* __restrict__ cbuf,
                          const float* __restrict__ biasP,
                          float* __restrict__ out, int t){
  __shared__ float glds[64 * 17];
  int tid = threadIdx.x, lane = tid & 63, w = tid >> 6;
  int blk = blockIdx.x;
  int rl = lane & 15, kg = lane >> 4;
  int arow = w * 16 + rl;          // batch row for A operand
  int pcol = blk * 16 + rl;        // packed gate-col for B operand

  f32x4 acc0 = {}, acc1 = {};
  const unsigned short* hrow = h_in + (size_t)arow * 1024 + kg * 8;
  const unsigned short* wrow = WhB + (size_t)pcol * 1024 + kg * 8;
  #pragma unroll 4
  for (int kk = 0; kk < 1024; kk += 64){
    bf16x8 a0 = *(const bf16x8*)(hrow + kk);
    bf16x8 b0 = *(const bf16x8*)(wrow + kk);
    bf16x8 a1 = *(const bf16x8*)(hrow + kk + 32);
    bf16x8 b1 = *(const bf16x8*)(wrow + kk + 32);
    acc0 = __builtin_amdgcn_mfma_f32_16x16x32_bf16(a0, b0, acc0, 0, 0, 0);
    acc1 = __builtin_amdgcn_mfma_f32_16x16x32_bf16(a1, b1, acc1, 0, 0, 0);
  }
  if (emb_t){  // fused x-contribution (fallback when ws too small for xg)
    const float* xrow = emb_t + (size_t)arow * 1024 + kg * 8;
    const unsigned short* wxrow = WxB + (size_t)pcol * 1024 + kg * 8;
    #pragma unroll 4
    for (int kk = 0; kk < 1024; kk += 64){
      bf16x8 a0 = cvt_f8(xrow + kk);
      bf16x8 b0 = *(const bf16x8*)(wxrow + kk);
      bf16x8 a1 = cvt_f8(xrow + kk + 32);
      bf16x8 b1 = *(const bf16x8*)(wxrow + kk + 32);
      acc0 = __builtin_amdgcn_mfma_f32_16x16x32_bf16(a0, b0, acc0, 0, 0, 0);
      acc1 = __builtin_amdgcn_mfma_f32_16x16x32_bf16(a1, b1, acc1, 0, 0, 0);
    }
  }
  f32x4 acc = acc0 + acc1;

  // scatter gate pre-activations to LDS; C/D: col=lane&15, row=(lane>>4)*4+r
  #pragma unroll
  for (int r = 0; r < 4; ++r){
    int brow = w * 16 + kg * 4 + r;
    float gval = acc[r];
    if (xg_t) gval += xg_t[(size_t)brow * G_DIM + blk * 16 + rl];
    glds[brow * 17 + rl] = gval;
  }
  __syncthreads();

  // elementwise LSTM update: thread -> (batch b, hidden jj within block)
  int b = tid >> 2, jj = tid & 3;
  int j = blk * 4 + jj;
  int pbase = blk * 16 + jj * 4;
  float gf = glds[b*17 + jj*4 + 0] + biasP[pbase + 0];
  float gi = glds[b*17 + jj*4 + 1] + biasP[pbase + 1];
  float go = glds[b*17 + jj*4 + 2] + biasP[pbase + 2];
  float gc = glds[b*17 + jj*4 + 3] + biasP[pbase + 3];
  float f  = 1.f / (1.f + __expf(-gf));
  float i_ = 1.f / (1.f + __expf(-gi));
  float o  = 1.f / (1.f + __expf(-go));
  float ct = tanhf(gc);
  float c_old = cbuf[b * H_DIM + j];
  float cn = f * c_old + i_ * ct;
  float hn = o * tanhf(cn);
  cbuf[b * H_DIM + j] = cn;
  h_out[b * H_DIM + j] = f2b(hn);
  out[((size_t)b * T_DIM + t) * H_DIM + j] = hn;   // out is [B, T, H]
}

// ---------------- launch ----------------
extern "C" void kernel_launch(void* const* d_in, const int* in_sizes, int n_in,
                              void* d_out, int out_size, void* d_ws, size_t ws_size,
                              hipStream_t stream){
  (void)in_sizes; (void)n_in; (void)out_size;
  const float* emb = (const float*)d_in[0];
  const float* Wf  = (const float*)d_in[1];
  const float* bfv = (const float*)d_in[2];
  const float* Wi  = (const float*)d_in[3];
  const float* biv = (const float*)d_in[4];
  const float* Wo  = (const float*)d_in[5];
  const float* bov = (const float*)d_in[6];
  const float* Wc  = (const float*)d_in[7];
  const float* bcv = (const float*)d_in[8];
  float* out = (float*)d_out;

  char* ws = (char*)d_ws;
  size_t off = 0;
  auto alloc = [&](size_t bytes) -> void* {
    void* p = ws + off; off += (bytes + 255) & ~(size_t)255; return p;
  };
  unsigned short* WxB   = (unsigned short*)alloc((size_t)G_DIM * 1024 * 2);
  unsigned short* WhB   = (unsigned short*)alloc((size_t)G_DIM * 1024 * 2);
  float*          biasP = (float*)alloc((size_t)G_DIM * 4);
  unsigned short* h0    = (unsigned short*)alloc((size_t)B_DIM * H_DIM * 2);
  unsigned short* h1    = (unsigned short*)alloc((size_t)B_DIM * H_DIM * 2);
  float*          cbuf  = (float*)alloc((size_t)B_DIM * H_DIM * 4);
  size_t base_end = off;
  const size_t embB_sz = (size_t)T_DIM * B_DIM * E_DIM * 2;      // 64 MB
  const size_t xg_sz   = (size_t)T_DIM * B_DIM * G_DIM * 4;      // 512 MB
  bool precompute = (ws_size >= base_end + embB_sz + xg_sz + 1024);
  unsigned short* embB = nullptr;
  float* xg = nullptr;
  if (precompute){
    embB = (unsigned short*)alloc(embB_sz);
    xg   = (float*)alloc(xg_sz);
  }

  pack_weights<<<G_DIM, 256, 0, stream>>>(Wf, Wi, Wo, Wc, bfv, biv, bov, bcv, WxB, WhB, biasP);
  zero_state<<<256, 256, 0, stream>>>(h0, h1, cbuf);
  if (precompute){
    conv_emb<<<2048, 256, 0, stream>>>(emb, embB);
    gemm_xg<<<dim3(256, 32), 256, 0, stream>>>(embB, WxB, xg);
  }
  for (int t = 0; t < T_DIM; ++t){
    const unsigned short* hin = (t & 1) ? h1 : h0;
    unsigned short*      hout = (t & 1) ? h0 : h1;
    lstm_step<<<256, 256, 0, stream>>>(
        WhB, WxB,
        precompute ? (xg + (size_t)t * B_DIM * G_DIM) : nullptr,
        precompute ? nullptr : (emb + (size_t)t * B_DIM * E_DIM),
        hin, hout, cbuf, biasP, out, t);
  }
}

// Round 3
// 10810.679 us; speedup vs baseline: 1.0959x; 1.0959x over previous
//
#include <hip/hip_runtime.h>
#include <hip/hip_cooperative_groups.h>
#include <stdint.h>

namespace cg = cooperative_groups;

#define T_DIM 512
#define B_DIM 64
#define E_DIM 1024
#define H_DIM 1024
#define G_DIM 4096   // 4*H, packed as p = j*4 + gate
#define NBLK 64      // persistent scan blocks (<= CU count, 1 block/CU by LDS)
#define CPB  64      // packed gate-cols per scan block (= 16 hidden units)

typedef short bf16x8 __attribute__((ext_vector_type(8)));
typedef float f32x4 __attribute__((ext_vector_type(4)));

__device__ __forceinline__ unsigned short f2b(float f){
  union{float f; unsigned u;} v; v.f = f;
  unsigned r = (v.u + 0x7FFFu + ((v.u >> 16) & 1u)) >> 16;  // RNE
  return (unsigned short)r;
}
__device__ __forceinline__ float b2f(unsigned short u){
  union{unsigned u; float f;} v; v.u = ((unsigned)u) << 16; return v.f;
}
__device__ __forceinline__ float fsigmoid(float x){
  return 1.f / (1.f + __expf(-x));
}
__device__ __forceinline__ float ftanh(float x){
  return 2.f / (1.f + __expf(-2.f * x)) - 1.f;
}

// ---------------- prep kernels ----------------

__global__ void pack_weights(const float* __restrict__ Wf, const float* __restrict__ Wi,
                             const float* __restrict__ Wo, const float* __restrict__ Wc,
                             const float* __restrict__ bfv, const float* __restrict__ biv,
                             const float* __restrict__ bov, const float* __restrict__ bcv,
                             unsigned short* __restrict__ WxB, unsigned short* __restrict__ WhB,
                             float* __restrict__ biasP){
  int p = blockIdx.x;            // 0..4095
  int j = p >> 2, g = p & 3;
  const float* W    = (g==0)?Wf:(g==1)?Wi:(g==2)?Wo:Wc;
  const float* bsrc = (g==0)?bfv:(g==1)?biv:(g==2)?bov:bcv;
  const float* wrow = W + (size_t)j * 2048;
  int t = threadIdx.x;           // 256 threads, 4 k each
  float4 x = *(const float4*)(wrow + 4*t);
  float4 h = *(const float4*)(wrow + 1024 + 4*t);
  ushort4 xo = make_ushort4(f2b(x.x), f2b(x.y), f2b(x.z), f2b(x.w));
  ushort4 ho = make_ushort4(f2b(h.x), f2b(h.y), f2b(h.z), f2b(h.w));
  *(ushort4*)&WxB[(size_t)p*1024 + 4*t] = xo;
  *(ushort4*)&WhB[(size_t)p*1024 + 4*t] = ho;
  if (t == 0) biasP[p] = bsrc[j];
}

__global__ void conv_emb(const float* __restrict__ emb, unsigned short* __restrict__ embB,
                         size_t n4){
  for (size_t i = (size_t)blockIdx.x * blockDim.x + threadIdx.x; i < n4;
       i += (size_t)gridDim.x * blockDim.x){
    float4 v = ((const float4*)emb)[i];
    ((ushort4*)embB)[i] = make_ushort4(f2b(v.x), f2b(v.y), f2b(v.z), f2b(v.w));
  }
}

__global__ void zero_state(unsigned short* __restrict__ h0, unsigned short* __restrict__ h1,
                           float* __restrict__ c){
  int i = blockIdx.x * blockDim.x + threadIdx.x;  // 65536 threads exactly
  h0[i] = 0; h1[i] = 0; c[i] = 0.f;
}

// ---------------- big GEMM: xg_chunk = embB @ WxB^T (bf16 out) ----------------
// A: [M][1024] bf16 row-major. B: [4096][1024] bf16 row-major (row = output col).
// C: [M][4096] bf16. Tile 128x128, BK=32, 4 waves (2x2), each wave 64x64.
__launch_bounds__(256)
__global__ void gemm_xg(const unsigned short* __restrict__ A,
                        const unsigned short* __restrict__ B,
                        unsigned short* __restrict__ C){
  __shared__ unsigned short Al[128*32];
  __shared__ unsigned short Bl[128*32];
  int m0 = blockIdx.x * 128, n0 = blockIdx.y * 128;
  int tid = threadIdx.x, lane = tid & 63, wid = tid >> 6;
  int mblk = (wid >> 1) * 64, nblk = (wid & 1) * 64;
  int rl = lane & 15, kg = lane >> 4;
  f32x4 acc[4][4] = {};

  for (int kk = 0; kk < 1024; kk += 32){
    {
      int c0 = tid, c1 = tid + 256;
      int r = c0 >> 2, g = c0 & 3, s = g ^ ((r >> 1) & 3);
      *(uint4*)&Al[r*32 + s*8] = *(const uint4*)&A[(size_t)(m0 + r)*1024 + kk + g*8];
      *(uint4*)&Bl[r*32 + s*8] = *(const uint4*)&B[(size_t)(n0 + r)*1024 + kk + g*8];
      r = c1 >> 2; g = c1 & 3; s = g ^ ((r >> 1) & 3);
      *(uint4*)&Al[r*32 + s*8] = *(const uint4*)&A[(size_t)(m0 + r)*1024 + kk + g*8];
      *(uint4*)&Bl[r*32 + s*8] = *(const uint4*)&B[(size_t)(n0 + r)*1024 + kk + g*8];
    }
    __syncthreads();
    bf16x8 a[4], b[4];
    #pragma unroll
    for (int mf = 0; mf < 4; ++mf){
      int r = mblk + mf*16 + rl;
      a[mf] = *(const bf16x8*)&Al[r*32 + (kg ^ ((r >> 1) & 3))*8];
    }
    #pragma unroll
    for (int nf = 0; nf < 4; ++nf){
      int r = nblk + nf*16 + rl;
      b[nf] = *(const bf16x8*)&Bl[r*32 + (kg ^ ((r >> 1) & 3))*8];
    }
    #pragma unroll
    for (int mf = 0; mf < 4; ++mf)
      #pragma unroll
      for (int nf = 0; nf < 4; ++nf)
        acc[mf][nf] = __builtin_amdgcn_mfma_f32_16x16x32_bf16(a[mf], b[nf], acc[mf][nf], 0, 0, 0);
    __syncthreads();
  }

  // C/D layout (m89-verified): col = lane&15, row = (lane>>4)*4 + reg
  int rq = kg * 4;
  #pragma unroll
  for (int mf = 0; mf < 4; ++mf)
    #pragma unroll
    for (int nf = 0; nf < 4; ++nf){
      int col = n0 + nblk + nf*16 + rl;
      #pragma unroll
      for (int r = 0; r < 4; ++r){
        int row = m0 + mblk + mf*16 + rq + r;
        C[(size_t)row * G_DIM + col] = f2b(acc[mf][nf][r]);
      }
    }
}

// ---------------- persistent recurrent scan (cooperative) ----------------
// NBLK=64 blocks x 256 threads, 1 block/CU (148 KB LDS). Block blk owns packed
// cols [blk*64, blk*64+64) = hidden units [blk*16, blk*16+16).
// Wh slice staged once into LDS fragment-major (conflict-free ds_read_b128).
// c lives in registers for [t0,t1), persisted in cglob across chunk launches.
// Grid-wide sync per step via cg::this_grid().sync() (cooperative launch).
__launch_bounds__(256, 1)
__global__ void lstm_scan(const unsigned short* __restrict__ WhB,
                          const unsigned short* __restrict__ xgc,  // bf16 [t1-t0][B][G]
                          const float* __restrict__ biasP,
                          unsigned short* __restrict__ hb0,
                          unsigned short* __restrict__ hb1,
                          float* __restrict__ cglob,
                          float* __restrict__ out,
                          int t0, int t1){
  cg::grid_group grid = cg::this_grid();
  __shared__ unsigned short Wl[4*32*64*8];   // 128 KB, frag-major [ct][kc][lane][8]
  __shared__ float gl[64][68];               // 17 KB gate staging (+pad)

  const int tid = threadIdx.x;
  const int blk = blockIdx.x;
  const int lane = tid & 63, wid = tid >> 6;
  const int bq = wid & 1, cq = wid >> 1;     // wave -> batch 32*bq, cols 32*cq
  const int rl = lane & 15, kg = lane >> 4;

  // One-time: stage Wh fragments (A/B use the SAME (lane,reg)->k map as MFMA reads)
  for (int idx = tid; idx < 4*32*64; idx += 256){
    int ct = idx >> 11;            // 16-col tile 0..3
    int kc = (idx >> 6) & 31;      // k-chunk of 32
    int l  = idx & 63;
    int col = ct*16 + (l & 15);
    int k   = kc*32 + (l >> 4)*8;
    *(bf16x8*)&Wl[idx*8] = *(const bf16x8*)&WhB[(size_t)(blk*CPB + col)*1024 + k];
  }

  // elementwise mapping: thread -> (batch bb, 16 consecutive packed cols at cb)
  const int bb = tid >> 2, cb = (tid & 3) * 16;
  const int jb = blk*16 + (tid & 3)*4;       // 4 hidden units owned by this thread
  f32x4 bias[4];
  #pragma unroll
  for (int p = 0; p < 4; ++p)
    bias[p] = *(const f32x4*)&biasP[blk*CPB + cb + p*4];
  f32x4 cv = *(const f32x4*)&cglob[(size_t)bb*H_DIM + jb];

  __syncthreads();

  const unsigned short* w0base = &Wl[(size_t)((2*cq + 0)*32)*64*8 + lane*8];
  const unsigned short* w1base = &Wl[(size_t)((2*cq + 1)*32)*64*8 + lane*8];

  for (int t = t0; t < t1; ++t){
    const unsigned short* hin = (t & 1) ? hb1 : hb0;
    unsigned short* hout = (t & 1) ? hb0 : hb1;

    // prefetch this thread's xg slice (independent of h)
    const unsigned short* xgp = xgc + ((size_t)(t - t0)*B_DIM + bb)*G_DIM + blk*CPB + cb;
    bf16x8 xr0 = *(const bf16x8*)xgp;
    bf16x8 xr1 = *(const bf16x8*)(xgp + 8);

    // wave GEMM: batch [32bq,+32) x cols [32cq,+32), K=1024, 4 acc chains
    f32x4 acc00 = {}, acc01 = {}, acc10 = {}, acc11 = {};
    const unsigned short* a0p = hin + (size_t)(32*bq + rl)*1024 + kg*8;
    const unsigned short* a1p = a0p + 16*1024;
    #pragma unroll 8
    for (int kc = 0; kc < 32; ++kc){
      bf16x8 af0 = *(const bf16x8*)(a0p + kc*32);
      bf16x8 af1 = *(const bf16x8*)(a1p + kc*32);
      bf16x8 bf0 = *(const bf16x8*)(w0base + kc*512);
      bf16x8 bf1 = *(const bf16x8*)(w1base + kc*512);
      acc00 = __builtin_amdgcn_mfma_f32_16x16x32_bf16(af0, bf0, acc00, 0, 0, 0);
      acc10 = __builtin_amdgcn_mfma_f32_16x16x32_bf16(af1, bf0, acc10, 0, 0, 0);
      acc01 = __builtin_amdgcn_mfma_f32_16x16x32_bf16(af0, bf1, acc01, 0, 0, 0);
      acc11 = __builtin_amdgcn_mfma_f32_16x16x32_bf16(af1, bf1, acc11, 0, 0, 0);
    }

    // scatter to LDS; C/D: col=lane&15, row=(lane>>4)*4+reg (m89-verified)
    {
      int r0 = 32*bq + kg*4, c0c = 32*cq + rl;
      #pragma unroll
      for (int r = 0; r < 4; ++r){
        gl[r0 +      r][c0c     ] = acc00[r];
        gl[r0 + 16 + r][c0c     ] = acc10[r];
        gl[r0 +      r][c0c + 16] = acc01[r];
        gl[r0 + 16 + r][c0c + 16] = acc11[r];
      }
    }
    __syncthreads();

    // elementwise gates: thread handles 4 hidden units (cb..cb+15 packed cols)
    ushort4 hu;
    f32x4 ov;
    {
      f32x4 g0, g1, g2, g3;
      #pragma unroll
      for (int e = 0; e < 4; ++e){
        g0[e] = gl[bb][cb +  0 + e] + b2f(xr0[e])     + bias[0][e];
        g1[e] = gl[bb][cb +  4 + e] + b2f(xr0[4 + e]) + bias[1][e];
        g2[e] = gl[bb][cb +  8 + e] + b2f(xr1[e])     + bias[2][e];
        g3[e] = gl[bb][cb + 12 + e] + b2f(xr1[4 + e]) + bias[3][e];
      }
      float f, i_, o, ct_, hn;
      f = fsigmoid(g0[0]); i_ = fsigmoid(g0[1]); o = fsigmoid(g0[2]); ct_ = ftanh(g0[3]);
      cv[0] = f*cv[0] + i_*ct_; hn = o*ftanh(cv[0]); hu.x = f2b(hn); ov[0] = hn;
      f = fsigmoid(g1[0]); i_ = fsigmoid(g1[1]); o = fsigmoid(g1[2]); ct_ = ftanh(g1[3]);
      cv[1] = f*cv[1] + i_*ct_; hn = o*ftanh(cv[1]); hu.y = f2b(hn); ov[1] = hn;
      f = fsigmoid(g2[0]); i_ = fsigmoid(g2[1]); o = fsigmoid(g2[2]); ct_ = ftanh(g2[3]);
      cv[2] = f*cv[2] + i_*ct_; hn = o*ftanh(cv[2]); hu.z = f2b(hn); ov[2] = hn;
      f = fsigmoid(g3[0]); i_ = fsigmoid(g3[1]); o = fsigmoid(g3[2]); ct_ = ftanh(g3[3]);
      cv[3] = f*cv[3] + i_*ct_; hn = o*ftanh(cv[3]); hu.w = f2b(hn); ov[3] = hn;
    }
    *(ushort4*)&hout[(size_t)bb*H_DIM + jb] = hu;
    *(f32x4*)&out[((size_t)bb*T_DIM + t)*H_DIM + jb] = ov;

    // grid-wide barrier with correct cross-XCD fencing (cooperative launch)
    grid.sync();
  }

  *(f32x4*)&cglob[(size_t)bb*H_DIM + jb] = cv;
}

// ---------------- round-1 proven fallback: per-step launched kernel ----------------
__device__ __forceinline__ bf16x8 cvt_f8(const float* p){
  float4 u = *(const float4*)p;
  float4 v = *(const float4*)(p + 4);
  bf16x8 r;
  r[0] = (short)f2b(u.x); r[1] = (short)f2b(u.y); r[2] = (short)f2b(u.z); r[3] = (short)f2b(u.w);
  r[4] = (short)f2b(v.x); r[5] = (short)f2b(v.y); r[6] = (short)f2b(v.z); r[7] = (short)f2b(v.w);
  return r;
}

__launch_bounds__(256)
__global__ void lstm_step(const unsigned short* __restrict__ WhB,
                          const unsigned short* __restrict__ WxB,
                          const float* __restrict__ emb_t,
                          const unsigned short* __restrict__ h_in,
                          unsigned short* __restrict__ h_out,
                          float* __restrict__ cbuf,
                          const float* __restrict__ biasP,
                          float* __restrict__ out, int t){
  __shared__ float glds[64 * 17];
  int tid = threadIdx.x, lane = tid & 63, w = tid >> 6;
  int blk = blockIdx.x;
  int rl = lane & 15, kg = lane >> 4;
  int arow = w * 16 + rl;
  int pcol = blk * 16 + rl;

  f32x4 acc0 = {}, acc1 = {};
  const unsigned short* hrow = h_in + (size_t)arow * 1024 + kg * 8;
  const unsigned short* wrow = WhB + (size_t)pcol * 1024 + kg * 8;
  #pragma unroll 4
  for (int kk = 0; kk < 1024; kk += 64){
    bf16x8 a0 = *(const bf16x8*)(hrow + kk);
    bf16x8 b0 = *(const bf16x8*)(wrow + kk);
    bf16x8 a1 = *(const bf16x8*)(hrow + kk + 32);
    bf16x8 b1 = *(const bf16x8*)(wrow + kk + 32);
    acc0 = __builtin_amdgcn_mfma_f32_16x16x32_bf16(a0, b0, acc0, 0, 0, 0);
    acc1 = __builtin_amdgcn_mfma_f32_16x16x32_bf16(a1, b1, acc1, 0, 0, 0);
  }
  {
    const float* xrow = emb_t + (size_t)arow * 1024 + kg * 8;
    const unsigned short* wxrow = WxB + (size_t)pcol * 1024 + kg * 8;
    #pragma unroll 4
    for (int kk = 0; kk < 1024; kk += 64){
      bf16x8 a0 = cvt_f8(xrow + kk);
      bf16x8 b0 = *(const bf16x8*)(wxrow + kk);
      bf16x8 a1 = cvt_f8(xrow + kk + 32);
      bf16x8 b1 = *(const bf16x8*)(wxrow + kk + 32);
      acc0 = __builtin_amdgcn_mfma_f32_16x16x32_bf16(a0, b0, acc0, 0, 0, 0);
      acc1 = __builtin_amdgcn_mfma_f32_16x16x32_bf16(a1, b1, acc1, 0, 0, 0);
    }
  }
  f32x4 acc = acc0 + acc1;

  #pragma unroll
  for (int r = 0; r < 4; ++r){
    int brow = w * 16 + kg * 4 + r;
    glds[brow * 17 + rl] = acc[r];
  }
  __syncthreads();

  int b = tid >> 2, jj = tid & 3;
  int j = blk * 4 + jj;
  int pbase = blk * 16 + jj * 4;
  float gf = glds[b*17 + jj*4 + 0] + biasP[pbase + 0];
  float gi = glds[b*17 + jj*4 + 1] + biasP[pbase + 1];
  float go = glds[b*17 + jj*4 + 2] + biasP[pbase + 2];
  float gc = glds[b*17 + jj*4 + 3] + biasP[pbase + 3];
  float f  = fsigmoid(gf);
  float i_ = fsigmoid(gi);
  float o  = fsigmoid(go);
  float ct = ftanh(gc);
  float c_old = cbuf[b * H_DIM + j];
  float cn = f * c_old + i_ * ct;
  float hn = o * ftanh(cn);
  cbuf[b * H_DIM + j] = cn;
  h_out[b * H_DIM + j] = f2b(hn);
  out[((size_t)b * T_DIM + t) * H_DIM + j] = hn;
}

// ---------------- launch ----------------
extern "C" void kernel_launch(void* const* d_in, const int* in_sizes, int n_in,
                              void* d_out, int out_size, void* d_ws, size_t ws_size,
                              hipStream_t stream){
  (void)in_sizes; (void)n_in; (void)out_size;
  const float* emb = (const float*)d_in[0];
  const float* Wf  = (const float*)d_in[1];
  const float* bfv = (const float*)d_in[2];
  const float* Wi  = (const float*)d_in[3];
  const float* biv = (const float*)d_in[4];
  const float* Wo  = (const float*)d_in[5];
  const float* bov = (const float*)d_in[6];
  const float* Wc  = (const float*)d_in[7];
  const float* bcv = (const float*)d_in[8];
  float* out = (float*)d_out;

  char* ws = (char*)d_ws;
  size_t off = 0;
  auto alloc = [&](size_t bytes) -> void* {
    void* p = ws + off; off += (bytes + 255) & ~(size_t)255; return p;
  };
  unsigned short* WxB   = (unsigned short*)alloc((size_t)G_DIM * 1024 * 2);
  unsigned short* WhB   = (unsigned short*)alloc((size_t)G_DIM * 1024 * 2);
  float*          biasP = (float*)alloc((size_t)G_DIM * 4);
  unsigned short* h0    = (unsigned short*)alloc((size_t)B_DIM * H_DIM * 2);
  unsigned short* h1    = (unsigned short*)alloc((size_t)B_DIM * H_DIM * 2);
  float*          cglob = (float*)alloc((size_t)B_DIM * H_DIM * 4);
  size_t base_end = off;

  // choose largest T-chunk whose embB(bf16) + xg(bf16) buffers fit in d_ws
  int Tc = 0;
  const int cands[6] = {512, 256, 128, 64, 32, 16};
  for (int ci = 0; ci < 6; ++ci){
    size_t need = base_end
                + (size_t)cands[ci] * B_DIM * E_DIM * 2   // embB chunk
                + (size_t)cands[ci] * B_DIM * G_DIM * 2   // xg chunk (bf16)
                + 4096;
    if (ws_size >= need){ Tc = cands[ci]; break; }
  }
  unsigned short* embB = nullptr;
  unsigned short* xgc  = nullptr;
  if (Tc > 0){
    embB = (unsigned short*)alloc((size_t)Tc * B_DIM * E_DIM * 2);
    xgc  = (unsigned short*)alloc((size_t)Tc * B_DIM * G_DIM * 2);
  }

  pack_weights<<<G_DIM, 256, 0, stream>>>(Wf, Wi, Wo, Wc, bfv, biv, bov, bcv, WxB, WhB, biasP);
  zero_state<<<256, 256, 0, stream>>>(h0, h1, cglob);

  if (Tc > 0){
    for (int t0 = 0; t0 < T_DIM; t0 += Tc){
      conv_emb<<<2048, 256, 0, stream>>>(emb + (size_t)t0 * B_DIM * E_DIM, embB,
                                         (size_t)Tc * B_DIM * E_DIM / 4);
      gemm_xg<<<dim3(Tc * B_DIM / 128, G_DIM / 128), 256, 0, stream>>>(embB, WxB, xgc);
      int t0v = t0, t1v = t0 + Tc;
      void* args[] = {(void*)&WhB, (void*)&xgc, (void*)&biasP, (void*)&h0, (void*)&h1,
                      (void*)&cglob, (void*)&out, (void*)&t0v, (void*)&t1v};
      hipLaunchCooperativeKernel((const void*)lstm_scan, dim3(NBLK), dim3(256),
                                 args, 0, stream);
    }
  } else {
    // round-1 proven fallback: fused per-step kernels (no big buffers needed)
    for (int t = 0; t < T_DIM; ++t){
      const unsigned short* hin = (t & 1) ? h1 : h0;
      unsigned short*      hout = (t & 1) ? h0 : h1;
      lstm_step<<<256, 256, 0, stream>>>(
          WhB, WxB, emb + (size_t)t * B_DIM * E_DIM, hin, hout, cglob, biasP, out, t);
    }
  }
}

// Round 4
// 9241.360 us; speedup vs baseline: 1.2820x; 1.1698x over previous
//
#include <hip/hip_runtime.h>
#include <stdint.h>

#define T_DIM 512
#define B_DIM 64
#define E_DIM 1024
#define H_DIM 1024
#define G_DIM 4096   // 4*H, packed as p = j*4 + gate
#define NBLK 64      // persistent scan blocks (1 block/CU by LDS; 64 <= 256 CUs)
#define CPB  64      // packed gate-cols per scan block (= 16 hidden units)

typedef short bf16x8 __attribute__((ext_vector_type(8)));
typedef float f32x4 __attribute__((ext_vector_type(4)));

__device__ __forceinline__ unsigned short f2b(float f){
  union{float f; unsigned u;} v; v.f = f;
  unsigned r = (v.u + 0x7FFFu + ((v.u >> 16) & 1u)) >> 16;  // RNE
  return (unsigned short)r;
}
__device__ __forceinline__ float b2f(unsigned short u){
  union{unsigned u; float f;} v; v.u = ((unsigned)u) << 16; return v.f;
}
__device__ __forceinline__ float fsigmoid(float x){
  return 1.f / (1.f + __expf(-x));
}
__device__ __forceinline__ float ftanh(float x){
  return 2.f / (1.f + __expf(-2.f * x)) - 1.f;
}

// 16B h-fragment load as 2x8B agent-scope relaxed atomics: emitted with
// coherence bits (sc1) so reads are served at the device-coherent point,
// never from a stale per-XCD L2. Required for cross-XCD h exchange.
__device__ __forceinline__ bf16x8 ld_h16(const unsigned short* p){
  union { unsigned long long q[2]; bf16x8 v; } u;
  u.q[0] = __hip_atomic_load((const unsigned long long*)p, __ATOMIC_RELAXED,
                             __HIP_MEMORY_SCOPE_AGENT);
  u.q[1] = __hip_atomic_load((const unsigned long long*)p + 1, __ATOMIC_RELAXED,
                             __HIP_MEMORY_SCOPE_AGENT);
  return u.v;
}

// ---------------- prep kernels ----------------

__global__ void pack_weights(const float* __restrict__ Wf, const float* __restrict__ Wi,
                             const float* __restrict__ Wo, const float* __restrict__ Wc,
                             const float* __restrict__ bfv, const float* __restrict__ biv,
                             const float* __restrict__ bov, const float* __restrict__ bcv,
                             unsigned short* __restrict__ WxB, unsigned short* __restrict__ WhB,
                             float* __restrict__ biasP){
  int p = blockIdx.x;            // 0..4095
  int j = p >> 2, g = p & 3;
  const float* W    = (g==0)?Wf:(g==1)?Wi:(g==2)?Wo:Wc;
  const float* bsrc = (g==0)?bfv:(g==1)?biv:(g==2)?bov:bcv;
  const float* wrow = W + (size_t)j * 2048;
  int t = threadIdx.x;           // 256 threads, 4 k each
  float4 x = *(const float4*)(wrow + 4*t);
  float4 h = *(const float4*)(wrow + 1024 + 4*t);
  ushort4 xo = make_ushort4(f2b(x.x), f2b(x.y), f2b(x.z), f2b(x.w));
  ushort4 ho = make_ushort4(f2b(h.x), f2b(h.y), f2b(h.z), f2b(h.w));
  *(ushort4*)&WxB[(size_t)p*1024 + 4*t] = xo;
  *(ushort4*)&WhB[(size_t)p*1024 + 4*t] = ho;
  if (t == 0) biasP[p] = bsrc[j];
}

__global__ void conv_emb(const float* __restrict__ emb, unsigned short* __restrict__ embB,
                         size_t n4){
  for (size_t i = (size_t)blockIdx.x * blockDim.x + threadIdx.x; i < n4;
       i += (size_t)gridDim.x * blockDim.x){
    float4 v = ((const float4*)emb)[i];
    ((ushort4*)embB)[i] = make_ushort4(f2b(v.x), f2b(v.y), f2b(v.z), f2b(v.w));
  }
}

__global__ void zero_state(unsigned short* __restrict__ h0, unsigned short* __restrict__ h1,
                           float* __restrict__ c, int* __restrict__ counter){
  int i = blockIdx.x * blockDim.x + threadIdx.x;  // 65536 threads exactly
  h0[i] = 0; h1[i] = 0; c[i] = 0.f;
  if (i == 0) *counter = 0;
}

// ---------------- big GEMM: xg_chunk = embB @ WxB^T (bf16 out) ----------------
__launch_bounds__(256)
__global__ void gemm_xg(const unsigned short* __restrict__ A,
                        const unsigned short* __restrict__ B,
                        unsigned short* __restrict__ C){
  __shared__ unsigned short Al[128*32];
  __shared__ unsigned short Bl[128*32];
  int m0 = blockIdx.x * 128, n0 = blockIdx.y * 128;
  int tid = threadIdx.x, lane = tid & 63, wid = tid >> 6;
  int mblk = (wid >> 1) * 64, nblk = (wid & 1) * 64;
  int rl = lane & 15, kg = lane >> 4;
  f32x4 acc[4][4] = {};

  for (int kk = 0; kk < 1024; kk += 32){
    {
      int c0 = tid, c1 = tid + 256;
      int r = c0 >> 2, g = c0 & 3, s = g ^ ((r >> 1) & 3);
      *(uint4*)&Al[r*32 + s*8] = *(const uint4*)&A[(size_t)(m0 + r)*1024 + kk + g*8];
      *(uint4*)&Bl[r*32 + s*8] = *(const uint4*)&B[(size_t)(n0 + r)*1024 + kk + g*8];
      r = c1 >> 2; g = c1 & 3; s = g ^ ((r >> 1) & 3);
      *(uint4*)&Al[r*32 + s*8] = *(const uint4*)&A[(size_t)(m0 + r)*1024 + kk + g*8];
      *(uint4*)&Bl[r*32 + s*8] = *(const uint4*)&B[(size_t)(n0 + r)*1024 + kk + g*8];
    }
    __syncthreads();
    bf16x8 a[4], b[4];
    #pragma unroll
    for (int mf = 0; mf < 4; ++mf){
      int r = mblk + mf*16 + rl;
      a[mf] = *(const bf16x8*)&Al[r*32 + (kg ^ ((r >> 1) & 3))*8];
    }
    #pragma unroll
    for (int nf = 0; nf < 4; ++nf){
      int r = nblk + nf*16 + rl;
      b[nf] = *(const bf16x8*)&Bl[r*32 + (kg ^ ((r >> 1) & 3))*8];
    }
    #pragma unroll
    for (int mf = 0; mf < 4; ++mf)
      #pragma unroll
      for (int nf = 0; nf < 4; ++nf)
        acc[mf][nf] = __builtin_amdgcn_mfma_f32_16x16x32_bf16(a[mf], b[nf], acc[mf][nf], 0, 0, 0);
    __syncthreads();
  }

  // C/D layout (m89-verified): col = lane&15, row = (lane>>4)*4 + reg
  int rq = kg * 4;
  #pragma unroll
  for (int mf = 0; mf < 4; ++mf)
    #pragma unroll
    for (int nf = 0; nf < 4; ++nf){
      int col = n0 + nblk + nf*16 + rl;
      #pragma unroll
      for (int r = 0; r < 4; ++r){
        int row = m0 + mblk + mf*16 + rq + r;
        C[(size_t)row * G_DIM + col] = f2b(acc[mf][nf][r]);
      }
    }
}

// ---------------- persistent recurrent scan (custom barrier) ----------------
// NBLK=64 blocks x 256 threads, 1 block/CU (148 KB LDS) -> all co-resident.
// Block blk owns packed cols [blk*64, +64) = hidden units [blk*16, +16).
// Wh slice staged once into LDS fragment-major (conflict-free ds_read_b128).
// c in registers. h exchange via agent-scope (sc1) relaxed atomics; barrier =
// vmcnt drain + leader fetch_add + tight spin (no L2 writeback/invalidate).
__launch_bounds__(256, 1)
__global__ void lstm_scan(const unsigned short* __restrict__ WhB,
                          const unsigned short* __restrict__ xgc,  // bf16 [t1-t0][B][G]
                          const float* __restrict__ biasP,
                          unsigned short* __restrict__ hb0,
                          unsigned short* __restrict__ hb1,
                          float* __restrict__ cglob,
                          float* __restrict__ out,
                          int* __restrict__ counter,
                          int t0, int t1){
  __shared__ unsigned short Wl[4*32*64*8];   // 128 KB, frag-major [ct][kc][lane][8]
  __shared__ float gl[64][68];               // 17 KB gate staging (+pad)

  const int tid = threadIdx.x;
  const int blk = blockIdx.x;
  const int lane = tid & 63, wid = tid >> 6;
  const int bq = wid & 1, cq = wid >> 1;     // wave -> batch 32*bq, cols 32*cq
  const int rl = lane & 15, kg = lane >> 4;

  // One-time: stage Wh fragments (A/B use the SAME (lane,reg)->k map as MFMA reads)
  for (int idx = tid; idx < 4*32*64; idx += 256){
    int ct = idx >> 11;            // 16-col tile 0..3
    int kc = (idx >> 6) & 31;      // k-chunk of 32
    int l  = idx & 63;
    int col = ct*16 + (l & 15);
    int k   = kc*32 + (l >> 4)*8;
    *(bf16x8*)&Wl[idx*8] = *(const bf16x8*)&WhB[(size_t)(blk*CPB + col)*1024 + k];
  }

  // elementwise mapping: thread -> (batch bb, 16 consecutive packed cols at cb)
  const int bb = tid >> 2, cb = (tid & 3) * 16;
  const int jb = blk*16 + (tid & 3)*4;       // 4 hidden units owned by this thread
  f32x4 bias[4];
  #pragma unroll
  for (int p = 0; p < 4; ++p)
    bias[p] = *(const f32x4*)&biasP[blk*CPB + cb + p*4];
  f32x4 cv = *(const f32x4*)&cglob[(size_t)bb*H_DIM + jb];

  __syncthreads();

  const unsigned short* w0base = &Wl[(size_t)((2*cq + 0)*32)*64*8 + lane*8];
  const unsigned short* w1base = &Wl[(size_t)((2*cq + 1)*32)*64*8 + lane*8];

  for (int t = t0; t < t1; ++t){
    const unsigned short* hin = (t & 1) ? hb1 : hb0;
    unsigned short* hout = (t & 1) ? hb0 : hb1;

    // prefetch this thread's xg slice (independent of h; HBM latency hides under GEMM)
    const unsigned short* xgp = xgc + ((size_t)(t - t0)*B_DIM + bb)*G_DIM + blk*CPB + cb;
    bf16x8 xr0 = *(const bf16x8*)xgp;
    bf16x8 xr1 = *(const bf16x8*)(xgp + 8);

    // wave GEMM: batch [32bq,+32) x cols [32cq,+32), K=1024, 4 acc chains.
    // A (h) loads are coherent-point reads (ld_h16).
    f32x4 acc00 = {}, acc01 = {}, acc10 = {}, acc11 = {};
    const unsigned short* a0p = hin + (size_t)(32*bq + rl)*1024 + kg*8;
    const unsigned short* a1p = a0p + 16*1024;
    #pragma unroll 8
    for (int kc = 0; kc < 32; ++kc){
      bf16x8 af0 = ld_h16(a0p + kc*32);
      bf16x8 af1 = ld_h16(a1p + kc*32);
      bf16x8 bf0 = *(const bf16x8*)(w0base + kc*512);
      bf16x8 bf1 = *(const bf16x8*)(w1base + kc*512);
      acc00 = __builtin_amdgcn_mfma_f32_16x16x32_bf16(af0, bf0, acc00, 0, 0, 0);
      acc10 = __builtin_amdgcn_mfma_f32_16x16x32_bf16(af1, bf0, acc10, 0, 0, 0);
      acc01 = __builtin_amdgcn_mfma_f32_16x16x32_bf16(af0, bf1, acc01, 0, 0, 0);
      acc11 = __builtin_amdgcn_mfma_f32_16x16x32_bf16(af1, bf1, acc11, 0, 0, 0);
    }

    // scatter to LDS; C/D: col=lane&15, row=(lane>>4)*4+reg (m89-verified)
    {
      int r0 = 32*bq + kg*4, c0c = 32*cq + rl;
      #pragma unroll
      for (int r = 0; r < 4; ++r){
        gl[r0 +      r][c0c     ] = acc00[r];
        gl[r0 + 16 + r][c0c     ] = acc10[r];
        gl[r0 +      r][c0c + 16] = acc01[r];
        gl[r0 + 16 + r][c0c + 16] = acc11[r];
      }
    }
    __syncthreads();

    // elementwise gates: thread handles 4 hidden units (cb..cb+15 packed cols)
    union { ushort4 s; unsigned long long q; } hu;
    f32x4 ov;
    {
      f32x4 g0, g1, g2, g3;
      #pragma unroll
      for (int e = 0; e < 4; ++e){
        g0[e] = gl[bb][cb +  0 + e] + b2f(xr0[e])     + bias[0][e];
        g1[e] = gl[bb][cb +  4 + e] + b2f(xr0[4 + e]) + bias[1][e];
        g2[e] = gl[bb][cb +  8 + e] + b2f(xr1[e])     + bias[2][e];
        g3[e] = gl[bb][cb + 12 + e] + b2f(xr1[4 + e]) + bias[3][e];
      }
      float f, i_, o, ct_, hn;
      f = fsigmoid(g0[0]); i_ = fsigmoid(g0[1]); o = fsigmoid(g0[2]); ct_ = ftanh(g0[3]);
      cv[0] = f*cv[0] + i_*ct_; hn = o*ftanh(cv[0]); hu.s.x = f2b(hn); ov[0] = hn;
      f = fsigmoid(g1[0]); i_ = fsigmoid(g1[1]); o = fsigmoid(g1[2]); ct_ = ftanh(g1[3]);
      cv[1] = f*cv[1] + i_*ct_; hn = o*ftanh(cv[1]); hu.s.y = f2b(hn); ov[1] = hn;
      f = fsigmoid(g2[0]); i_ = fsigmoid(g2[1]); o = fsigmoid(g2[2]); ct_ = ftanh(g2[3]);
      cv[2] = f*cv[2] + i_*ct_; hn = o*ftanh(cv[2]); hu.s.z = f2b(hn); ov[2] = hn;
      f = fsigmoid(g3[0]); i_ = fsigmoid(g3[1]); o = fsigmoid(g3[2]); ct_ = ftanh(g3[3]);
      cv[3] = f*cv[3] + i_*ct_; hn = o*ftanh(cv[3]); hu.s.w = f2b(hn); ov[3] = hn;
    }
    // h store at coherent point (sc1) so all XCDs see it next step
    __hip_atomic_store((unsigned long long*)&hout[(size_t)bb*H_DIM + jb], hu.q,
                       __ATOMIC_RELAXED, __HIP_MEMORY_SCOPE_AGENT);
    *(f32x4*)&out[((size_t)bb*T_DIM + t)*H_DIM + jb] = ov;

    // grid barrier (skip after final step): every thread drains its stores
    // (h at coherent point once vmcnt==0), then leader arrives + spins.
    if (t + 1 < t1){
      asm volatile("s_waitcnt vmcnt(0)" ::: "memory");
      __syncthreads();
      if (tid == 0){
        __hip_atomic_fetch_add(counter, 1, __ATOMIC_RELAXED, __HIP_MEMORY_SCOPE_AGENT);
        const int target = NBLK * (t + 1);   // counter monotonic across chunk launches
        while (__hip_atomic_load(counter, __ATOMIC_RELAXED, __HIP_MEMORY_SCOPE_AGENT) < target)
          __builtin_amdgcn_s_sleep(1);
      }
      __syncthreads();
      asm volatile("" ::: "memory");  // keep next-step loads below the spin
    }
  }

  *(f32x4*)&cglob[(size_t)bb*H_DIM + jb] = cv;
}

// ---------------- round-1 proven fallback: per-step launched kernel ----------------
__device__ __forceinline__ bf16x8 cvt_f8(const float* p){
  float4 u = *(const float4*)p;
  float4 v = *(const float4*)(p + 4);
  bf16x8 r;
  r[0] = (short)f2b(u.x); r[1] = (short)f2b(u.y); r[2] = (short)f2b(u.z); r[3] = (short)f2b(u.w);
  r[4] = (short)f2b(v.x); r[5] = (short)f2b(v.y); r[6] = (short)f2b(v.z); r[7] = (short)f2b(v.w);
  return r;
}

__launch_bounds__(256)
__global__ void lstm_step(const unsigned short* __restrict__ WhB,
                          const unsigned short* __restrict__ WxB,
                          const float* __restrict__ emb_t,
                          const unsigned short* __restrict__ h_in,
                          unsigned short* __restrict__ h_out,
                          float* __restrict__ cbuf,
                          const float* __restrict__ biasP,
                          float* __restrict__ out, int t){
  __shared__ float glds[64 * 17];
  int tid = threadIdx.x, lane = tid & 63, w = tid >> 6;
  int blk = blockIdx.x;
  int rl = lane & 15, kg = lane >> 4;
  int arow = w * 16 + rl;
  int pcol = blk * 16 + rl;

  f32x4 acc0 = {}, acc1 = {};
  const unsigned short* hrow = h_in + (size_t)arow * 1024 + kg * 8;
  const unsigned short* wrow = WhB + (size_t)pcol * 1024 + kg * 8;
  #pragma unroll 4
  for (int kk = 0; kk < 1024; kk += 64){
    bf16x8 a0 = *(const bf16x8*)(hrow + kk);
    bf16x8 b0 = *(const bf16x8*)(wrow + kk);
    bf16x8 a1 = *(const bf16x8*)(hrow + kk + 32);
    bf16x8 b1 = *(const bf16x8*)(wrow + kk + 32);
    acc0 = __builtin_amdgcn_mfma_f32_16x16x32_bf16(a0, b0, acc0, 0, 0, 0);
    acc1 = __builtin_amdgcn_mfma_f32_16x16x32_bf16(a1, b1, acc1, 0, 0, 0);
  }
  {
    const float* xrow = emb_t + (size_t)arow * 1024 + kg * 8;
    const unsigned short* wxrow = WxB + (size_t)pcol * 1024 + kg * 8;
    #pragma unroll 4
    for (int kk = 0; kk < 1024; kk += 64){
      bf16x8 a0 = cvt_f8(xrow + kk);
      bf16x8 b0 = *(const bf16x8*)(wxrow + kk);
      bf16x8 a1 = cvt_f8(xrow + kk + 32);
      bf16x8 b1 = *(const bf16x8*)(wxrow + kk + 32);
      acc0 = __builtin_amdgcn_mfma_f32_16x16x32_bf16(a0, b0, acc0, 0, 0, 0);
      acc1 = __builtin_amdgcn_mfma_f32_16x16x32_bf16(a1, b1, acc1, 0, 0, 0);
    }
  }
  f32x4 acc = acc0 + acc1;

  #pragma unroll
  for (int r = 0; r < 4; ++r){
    int brow = w * 16 + kg * 4 + r;
    glds[brow * 17 + rl] = acc[r];
  }
  __syncthreads();

  int b = tid >> 2, jj = tid & 3;
  int j = blk * 4 + jj;
  int pbase = blk * 16 + jj * 4;
  float gf = glds[b*17 + jj*4 + 0] + biasP[pbase + 0];
  float gi = glds[b*17 + jj*4 + 1] + biasP[pbase + 1];
  float go = glds[b*17 + jj*4 + 2] + biasP[pbase + 2];
  float gc = glds[b*17 + jj*4 + 3] + biasP[pbase + 3];
  float f  = fsigmoid(gf);
  float i_ = fsigmoid(gi);
  float o  = fsigmoid(go);
  float ct = ftanh(gc);
  float c_old = cbuf[b * H_DIM + j];
  float cn = f * c_old + i_ * ct;
  float hn = o * ftanh(cn);
  cbuf[b * H_DIM + j] = cn;
  h_out[b * H_DIM + j] = f2b(hn);
  out[((size_t)b * T_DIM + t) * H_DIM + j] = hn;
}

// ---------------- launch ----------------
extern "C" void kernel_launch(void* const* d_in, const int* in_sizes, int n_in,
                              void* d_out, int out_size, void* d_ws, size_t ws_size,
                              hipStream_t stream){
  (void)in_sizes; (void)n_in; (void)out_size;
  const float* emb = (const float*)d_in[0];
  const float* Wf  = (const float*)d_in[1];
  const float* bfv = (const float*)d_in[2];
  const float* Wi  = (const float*)d_in[3];
  const float* biv = (const float*)d_in[4];
  const float* Wo  = (const float*)d_in[5];
  const float* bov = (const float*)d_in[6];
  const float* Wc  = (const float*)d_in[7];
  const float* bcv = (const float*)d_in[8];
  float* out = (float*)d_out;

  char* ws = (char*)d_ws;
  size_t off = 0;
  auto alloc = [&](size_t bytes) -> void* {
    void* p = ws + off; off += (bytes + 255) & ~(size_t)255; return p;
  };
  unsigned short* WxB   = (unsigned short*)alloc((size_t)G_DIM * 1024 * 2);
  unsigned short* WhB   = (unsigned short*)alloc((size_t)G_DIM * 1024 * 2);
  float*          biasP = (float*)alloc((size_t)G_DIM * 4);
  unsigned short* h0    = (unsigned short*)alloc((size_t)B_DIM * H_DIM * 2);
  unsigned short* h1    = (unsigned short*)alloc((size_t)B_DIM * H_DIM * 2);
  float*          cglob = (float*)alloc((size_t)B_DIM * H_DIM * 4);
  int*            counter = (int*)alloc(256);
  size_t base_end = off;

  // choose largest T-chunk whose embB(bf16) + xg(bf16) buffers fit in d_ws
  int Tc = 0;
  const int cands[6] = {512, 256, 128, 64, 32, 16};
  for (int ci = 0; ci < 6; ++ci){
    size_t need = base_end
                + (size_t)cands[ci] * B_DIM * E_DIM * 2   // embB chunk
                + (size_t)cands[ci] * B_DIM * G_DIM * 2   // xg chunk (bf16)
                + 4096;
    if (ws_size >= need){ Tc = cands[ci]; break; }
  }
  unsigned short* embB = nullptr;
  unsigned short* xgc  = nullptr;
  if (Tc > 0){
    embB = (unsigned short*)alloc((size_t)Tc * B_DIM * E_DIM * 2);
    xgc  = (unsigned short*)alloc((size_t)Tc * B_DIM * G_DIM * 2);
  }

  pack_weights<<<G_DIM, 256, 0, stream>>>(Wf, Wi, Wo, Wc, bfv, biv, bov, bcv, WxB, WhB, biasP);
  zero_state<<<256, 256, 0, stream>>>(h0, h1, cglob, counter);

  if (Tc > 0){
    for (int t0 = 0; t0 < T_DIM; t0 += Tc){
      conv_emb<<<2048, 256, 0, stream>>>(emb + (size_t)t0 * B_DIM * E_DIM, embB,
                                         (size_t)Tc * B_DIM * E_DIM / 4);
      gemm_xg<<<dim3(Tc * B_DIM / 128, G_DIM / 128), 256, 0, stream>>>(embB, WxB, xgc);
      lstm_scan<<<NBLK, 256, 0, stream>>>(WhB, xgc, biasP, h0, h1, cglob, out,
                                          counter, t0, t0 + Tc);
    }
  } else {
    // round-1 proven fallback: fused per-step kernels (no big buffers needed)
    for (int t = 0; t < T_DIM; ++t){
      const unsigned short* hin = (t & 1) ? h1 : h0;
      unsigned short*      hout = (t & 1) ? h0 : h1;
      lstm_step<<<256, 256, 0, stream>>>(
          WhB, WxB, emb + (size_t)t * B_DIM * E_DIM, hin, hout, cglob, biasP, out, t);
    }
  }
}

// Round 5
// 6361.820 us; speedup vs baseline: 1.8622x; 1.4526x over previous
//
#include <hip/hip_runtime.h>
#include <stdint.h>

#define T_DIM 512
#define B_DIM 64
#define E_DIM 1024
#define H_DIM 1024
#define G_DIM 4096   // 4*H, packed as p = j*4 + gate
#define NBLK 64      // persistent scan blocks (1 block/CU by LDS; 64 <= 256 CUs)
#define CPB  64      // packed gate-cols per scan block (= 16 hidden units)

typedef short bf16x8 __attribute__((ext_vector_type(8)));
typedef float f32x4 __attribute__((ext_vector_type(4)));

__device__ __forceinline__ unsigned short f2b(float f){
  union{float f; unsigned u;} v; v.f = f;
  unsigned r = (v.u + 0x7FFFu + ((v.u >> 16) & 1u)) >> 16;  // RNE
  return (unsigned short)r;
}
__device__ __forceinline__ float b2f(unsigned short u){
  union{unsigned u; float f;} v; v.u = ((unsigned)u) << 16; return v.f;
}
__device__ __forceinline__ float fsigmoid(float x){
  return 1.f / (1.f + __expf(-x));
}
__device__ __forceinline__ float ftanh(float x){
  return 2.f / (1.f + __expf(-2.f * x)) - 1.f;
}

// 16B coherent load: sc0+sc1 bypass L1/L2 so the read is served at the
// device-coherent point (like the round-4 agent-scope atomics, which were
// verified correct) but 16B wide, non-atomic, with immediate offsets.
template<int OFF>
__device__ __forceinline__ bf16x8 ld_h16(const unsigned short* p){
  bf16x8 r;
  asm volatile("global_load_dwordx4 %0, %1, off offset:%2 sc0 sc1"
               : "=v"(r) : "v"(p), "i"(OFF) : "memory");
  return r;
}
// plain 16B load (xg: producer kernel boundary already flushed it)
__device__ __forceinline__ bf16x8 ld_g16(const unsigned short* p){
  bf16x8 r;
  asm volatile("global_load_dwordx4 %0, %1, off"
               : "=v"(r) : "v"(p) : "memory");
  return r;
}

#define LD8(dst, base, K0) \
  dst[0]=ld_h16<((K0)+0)*64>(base); dst[1]=ld_h16<((K0)+1)*64>(base); \
  dst[2]=ld_h16<((K0)+2)*64>(base); dst[3]=ld_h16<((K0)+3)*64>(base); \
  dst[4]=ld_h16<((K0)+4)*64>(base); dst[5]=ld_h16<((K0)+5)*64>(base); \
  dst[6]=ld_h16<((K0)+6)*64>(base); dst[7]=ld_h16<((K0)+7)*64>(base);

// wait until <=N vmem outstanding, then block MFMA/VALU hoisting above this
// point (rule #18); DS_READs (0x100) may still cross for overlap.
#define WAITV(N) \
  asm volatile("s_waitcnt vmcnt(" #N ")" ::: "memory"); \
  __builtin_amdgcn_sched_barrier(0x100);

#define MFMA_GRP(buf, G) \
  { _Pragma("unroll") \
    for (int u = 0; u < 8; ++u){ \
      bf16x8 b0 = *(const bf16x8*)(w0base + ((G)*8+u)*512); \
      bf16x8 b1 = *(const bf16x8*)(w1base + ((G)*8+u)*512); \
      if (u & 1){ acc0b = __builtin_amdgcn_mfma_f32_16x16x32_bf16(buf[u], b0, acc0b, 0,0,0); \
                  acc1b = __builtin_amdgcn_mfma_f32_16x16x32_bf16(buf[u], b1, acc1b, 0,0,0); } \
      else      { acc0a = __builtin_amdgcn_mfma_f32_16x16x32_bf16(buf[u], b0, acc0a, 0,0,0); \
                  acc1a = __builtin_amdgcn_mfma_f32_16x16x32_bf16(buf[u], b1, acc1a, 0,0,0); } \
    } }

// ---------------- prep kernels ----------------

__global__ void pack_weights(const float* __restrict__ Wf, const float* __restrict__ Wi,
                             const float* __restrict__ Wo, const float* __restrict__ Wc,
                             const float* __restrict__ bfv, const float* __restrict__ biv,
                             const float* __restrict__ bov, const float* __restrict__ bcv,
                             unsigned short* __restrict__ WxB, unsigned short* __restrict__ WhB,
                             float* __restrict__ biasP){
  int p = blockIdx.x;            // 0..4095
  int j = p >> 2, g = p & 3;
  const float* W    = (g==0)?Wf:(g==1)?Wi:(g==2)?Wo:Wc;
  const float* bsrc = (g==0)?bfv:(g==1)?biv:(g==2)?bov:bcv;
  const float* wrow = W + (size_t)j * 2048;
  int t = threadIdx.x;           // 256 threads, 4 k each
  float4 x = *(const float4*)(wrow + 4*t);
  float4 h = *(const float4*)(wrow + 1024 + 4*t);
  ushort4 xo = make_ushort4(f2b(x.x), f2b(x.y), f2b(x.z), f2b(x.w));
  ushort4 ho = make_ushort4(f2b(h.x), f2b(h.y), f2b(h.z), f2b(h.w));
  *(ushort4*)&WxB[(size_t)p*1024 + 4*t] = xo;
  *(ushort4*)&WhB[(size_t)p*1024 + 4*t] = ho;
  if (t == 0) biasP[p] = bsrc[j];
}

__global__ void conv_emb(const float* __restrict__ emb, unsigned short* __restrict__ embB,
                         size_t n4){
  for (size_t i = (size_t)blockIdx.x * blockDim.x + threadIdx.x; i < n4;
       i += (size_t)gridDim.x * blockDim.x){
    float4 v = ((const float4*)emb)[i];
    ((ushort4*)embB)[i] = make_ushort4(f2b(v.x), f2b(v.y), f2b(v.z), f2b(v.w));
  }
}

__global__ void zero_state(unsigned short* __restrict__ h0, unsigned short* __restrict__ h1,
                           float* __restrict__ c, int* __restrict__ counter){
  int i = blockIdx.x * blockDim.x + threadIdx.x;  // 65536 threads exactly
  h0[i] = 0; h1[i] = 0; c[i] = 0.f;
  if (i == 0) *counter = 0;
}

// ---------------- big GEMM: xg_chunk = embB @ WxB^T (bf16 out) ----------------
__launch_bounds__(256)
__global__ void gemm_xg(const unsigned short* __restrict__ A,
                        const unsigned short* __restrict__ B,
                        unsigned short* __restrict__ C){
  __shared__ unsigned short Al[128*32];
  __shared__ unsigned short Bl[128*32];
  int m0 = blockIdx.x * 128, n0 = blockIdx.y * 128;
  int tid = threadIdx.x, lane = tid & 63, wid = tid >> 6;
  int mblk = (wid >> 1) * 64, nblk = (wid & 1) * 64;
  int rl = lane & 15, kg = lane >> 4;
  f32x4 acc[4][4] = {};

  for (int kk = 0; kk < 1024; kk += 32){
    {
      int c0 = tid, c1 = tid + 256;
      int r = c0 >> 2, g = c0 & 3, s = g ^ ((r >> 1) & 3);
      *(uint4*)&Al[r*32 + s*8] = *(const uint4*)&A[(size_t)(m0 + r)*1024 + kk + g*8];
      *(uint4*)&Bl[r*32 + s*8] = *(const uint4*)&B[(size_t)(n0 + r)*1024 + kk + g*8];
      r = c1 >> 2; g = c1 & 3; s = g ^ ((r >> 1) & 3);
      *(uint4*)&Al[r*32 + s*8] = *(const uint4*)&A[(size_t)(m0 + r)*1024 + kk + g*8];
      *(uint4*)&Bl[r*32 + s*8] = *(const uint4*)&B[(size_t)(n0 + r)*1024 + kk + g*8];
    }
    __syncthreads();
    bf16x8 a[4], b[4];
    #pragma unroll
    for (int mf = 0; mf < 4; ++mf){
      int r = mblk + mf*16 + rl;
      a[mf] = *(const bf16x8*)&Al[r*32 + (kg ^ ((r >> 1) & 3))*8];
    }
    #pragma unroll
    for (int nf = 0; nf < 4; ++nf){
      int r = nblk + nf*16 + rl;
      b[nf] = *(const bf16x8*)&Bl[r*32 + (kg ^ ((r >> 1) & 3))*8];
    }
    #pragma unroll
    for (int mf = 0; mf < 4; ++mf)
      #pragma unroll
      for (int nf = 0; nf < 4; ++nf)
        acc[mf][nf] = __builtin_amdgcn_mfma_f32_16x16x32_bf16(a[mf], b[nf], acc[mf][nf], 0, 0, 0);
    __syncthreads();
  }

  // C/D layout (m89-verified): col = lane&15, row = (lane>>4)*4 + reg
  int rq = kg * 4;
  #pragma unroll
  for (int mf = 0; mf < 4; ++mf)
    #pragma unroll
    for (int nf = 0; nf < 4; ++nf){
      int col = n0 + nblk + nf*16 + rl;
      #pragma unroll
      for (int r = 0; r < 4; ++r){
        int row = m0 + mblk + mf*16 + rq + r;
        C[(size_t)row * G_DIM + col] = f2b(acc[mf][nf][r]);
      }
    }
}

// ---------------- persistent recurrent scan ----------------
// 64 blocks x 512 threads (8 waves, 2/SIMD for TLP latency hiding), 1 block/CU
// (148 KB LDS). Block blk owns packed cols [blk*64,+64) = hidden units
// [blk*16,+16). Wh in LDS fragment-major. h loads: 16B sc0/sc1 coherent loads,
// double-buffered register pipeline with counted vmcnt (T4). c in registers.
__launch_bounds__(512, 2)
__global__ void lstm_scan(const unsigned short* __restrict__ WhB,
                          const unsigned short* __restrict__ xgc,  // bf16 [t1-t0][B][G]
                          const float* __restrict__ biasP,
                          unsigned short* __restrict__ hb0,
                          unsigned short* __restrict__ hb1,
                          float* __restrict__ cglob,
                          float* __restrict__ out,
                          int* __restrict__ counter,
                          int t0, int t1){
  __shared__ unsigned short Wl[4*32*64*8];   // 128 KB, frag-major [ct][kc][lane][8]
  __shared__ float gl[64][68];               // 17 KB gate staging (+pad)

  const int tid = threadIdx.x;
  const int blk = blockIdx.x;
  const int lane = tid & 63, wid = tid >> 6;
  const int r16 = wid & 3, ch = wid >> 2;    // wave -> rows [16*r16,+16), cols [32*ch,+32)
  const int rl = lane & 15, kg = lane >> 4;

  // One-time: stage Wh fragments (A/B use the SAME (lane,reg)->k map as MFMA reads)
  for (int idx = tid; idx < 4*32*64; idx += 512){
    int ct = idx >> 11;            // 16-col tile 0..3
    int kc = (idx >> 6) & 31;      // k-chunk of 32
    int l  = idx & 63;
    int col = ct*16 + (l & 15);
    int k   = kc*32 + (l >> 4)*8;
    *(bf16x8*)&Wl[idx*8] = *(const bf16x8*)&WhB[(size_t)(blk*CPB + col)*1024 + k];
  }

  // elementwise mapping: thread -> (batch bb, 8 packed cols at cb = 2 hidden units)
  const int bb = tid >> 3, q = tid & 7, cb = q * 8;
  const int jb = blk*16 + q*2;               // 2 hidden units owned by this thread
  f32x4 biasA = *(const f32x4*)&biasP[blk*CPB + cb];
  f32x4 biasB = *(const f32x4*)&biasP[blk*CPB + cb + 4];
  float2 cv = *(const float2*)&cglob[(size_t)bb*H_DIM + jb];

  __syncthreads();
  asm volatile("s_waitcnt vmcnt(0)" ::: "memory");  // clean vmcnt before counted loop

  const unsigned short* w0base = &Wl[(size_t)((2*ch + 0)*32)*64*8 + lane*8];
  const unsigned short* w1base = &Wl[(size_t)((2*ch + 1)*32)*64*8 + lane*8];

  for (int t = t0; t < t1; ++t){
    const unsigned short* hin = (t & 1) ? hb1 : hb0;
    unsigned short* hout = (t & 1) ? hb0 : hb1;

    // --- counted-vmcnt pipelined GEMM: rows [16*r16,+16) x cols [32*ch,+32) ---
    const unsigned short* ap = hin + (size_t)(16*r16 + rl)*1024 + kg*8;
    const unsigned short* xgp = xgc + ((size_t)(t - t0)*B_DIM + bb)*G_DIM + blk*CPB + cb;

    bf16x8 xr = ld_g16(xgp);     // issued first; done by group0's wait
    bf16x8 aA[8], aB[8];
    LD8(aA, ap, 0);
    LD8(aB, ap, 8);
    f32x4 acc0a = {}, acc0b = {}, acc1a = {}, acc1b = {};

    WAITV(8);                    // xg + aA complete (aB outstanding)
    MFMA_GRP(aA, 0);
    LD8(aA, ap, 16);
    WAITV(8);                    // aB complete (new aA outstanding)
    MFMA_GRP(aB, 1);
    LD8(aB, ap, 24);
    WAITV(8);                    // new aA complete
    MFMA_GRP(aA, 2);
    WAITV(0);                    // everything complete
    MFMA_GRP(aB, 3);

    f32x4 acc0 = acc0a + acc0b;
    f32x4 acc1 = acc1a + acc1b;

    // scatter to LDS; C/D: col=lane&15, row=(lane>>4)*4+reg (m89-verified)
    {
      int r0 = 16*r16 + kg*4, c0c = 32*ch + rl;
      #pragma unroll
      for (int r = 0; r < 4; ++r){
        gl[r0 + r][c0c     ] = acc0[r];
        gl[r0 + r][c0c + 16] = acc1[r];
      }
    }
    __syncthreads();

    // elementwise gates: thread handles 2 hidden units (8 packed cols at cb)
    float hn0, hn1;
    {
      f32x4 gA = *(const f32x4*)&gl[bb][cb];
      f32x4 gB = *(const f32x4*)&gl[bb][cb + 4];
      #pragma unroll
      for (int e = 0; e < 4; ++e){
        gA[e] += b2f(xr[e])     + biasA[e];
        gB[e] += b2f(xr[4 + e]) + biasB[e];
      }
      float f, i_, o, ct_;
      f = fsigmoid(gA[0]); i_ = fsigmoid(gA[1]); o = fsigmoid(gA[2]); ct_ = ftanh(gA[3]);
      cv.x = f*cv.x + i_*ct_; hn0 = o*ftanh(cv.x);
      f = fsigmoid(gB[0]); i_ = fsigmoid(gB[1]); o = fsigmoid(gB[2]); ct_ = ftanh(gB[3]);
      cv.y = f*cv.y + i_*ct_; hn1 = o*ftanh(cv.y);
    }
    // h store at coherent point (sc1) so all XCDs see it next step
    unsigned hp = (unsigned)f2b(hn0) | ((unsigned)f2b(hn1) << 16);
    __hip_atomic_store((unsigned*)&hout[(size_t)bb*H_DIM + jb], hp,
                       __ATOMIC_RELAXED, __HIP_MEMORY_SCOPE_AGENT);
    float2 o2; o2.x = hn0; o2.y = hn1;
    *(float2*)&out[((size_t)bb*T_DIM + t)*H_DIM + jb] = o2;

    // grid barrier (skip after final step): drain stores, leader arrives+spins
    if (t + 1 < t1){
      asm volatile("s_waitcnt vmcnt(0)" ::: "memory");
      __syncthreads();
      if (tid == 0){
        __hip_atomic_fetch_add(counter, 1, __ATOMIC_RELAXED, __HIP_MEMORY_SCOPE_AGENT);
        const int target = NBLK * (t + 1);   // monotonic across chunk launches
        while (__hip_atomic_load(counter, __ATOMIC_RELAXED, __HIP_MEMORY_SCOPE_AGENT) < target)
          __builtin_amdgcn_s_sleep(1);
      }
      __syncthreads();
      asm volatile("" ::: "memory");  // keep next-step loads below the spin
    }
  }

  *(float2*)&cglob[(size_t)bb*H_DIM + jb] = cv;
}

// ---------------- round-1 proven fallback: per-step launched kernel ----------------
__device__ __forceinline__ bf16x8 cvt_f8(const float* p){
  float4 u = *(const float4*)p;
  float4 v = *(const float4*)(p + 4);
  bf16x8 r;
  r[0] = (short)f2b(u.x); r[1] = (short)f2b(u.y); r[2] = (short)f2b(u.z); r[3] = (short)f2b(u.w);
  r[4] = (short)f2b(v.x); r[5] = (short)f2b(v.y); r[6] = (short)f2b(v.z); r[7] = (short)f2b(v.w);
  return r;
}

__launch_bounds__(256)
__global__ void lstm_step(const unsigned short* __restrict__ WhB,
                          const unsigned short* __restrict__ WxB,
                          const float* __restrict__ emb_t,
                          const unsigned short* __restrict__ h_in,
                          unsigned short* __restrict__ h_out,
                          float* __restrict__ cbuf,
                          const float* __restrict__ biasP,
                          float* __restrict__ out, int t){
  __shared__ float glds[64 * 17];
  int tid = threadIdx.x, lane = tid & 63, w = tid >> 6;
  int blk = blockIdx.x;
  int rl = lane & 15, kg = lane >> 4;
  int arow = w * 16 + rl;
  int pcol = blk * 16 + rl;

  f32x4 acc0 = {}, acc1 = {};
  const unsigned short* hrow = h_in + (size_t)arow * 1024 + kg * 8;
  const unsigned short* wrow = WhB + (size_t)pcol * 1024 + kg * 8;
  #pragma unroll 4
  for (int kk = 0; kk < 1024; kk += 64){
    bf16x8 a0 = *(const bf16x8*)(hrow + kk);
    bf16x8 b0 = *(const bf16x8*)(wrow + kk);
    bf16x8 a1 = *(const bf16x8*)(hrow + kk + 32);
    bf16x8 b1 = *(const bf16x8*)(wrow + kk + 32);
    acc0 = __builtin_amdgcn_mfma_f32_16x16x32_bf16(a0, b0, acc0, 0, 0, 0);
    acc1 = __builtin_amdgcn_mfma_f32_16x16x32_bf16(a1, b1, acc1, 0, 0, 0);
  }
  {
    const float* xrow = emb_t + (size_t)arow * 1024 + kg * 8;
    const unsigned short* wxrow = WxB + (size_t)pcol * 1024 + kg * 8;
    #pragma unroll 4
    for (int kk = 0; kk < 1024; kk += 64){
      bf16x8 a0 = cvt_f8(xrow + kk);
      bf16x8 b0 = *(const bf16x8*)(wxrow + kk);
      bf16x8 a1 = cvt_f8(xrow + kk + 32);
      bf16x8 b1 = *(const bf16x8*)(wxrow + kk + 32);
      acc0 = __builtin_amdgcn_mfma_f32_16x16x32_bf16(a0, b0, acc0, 0, 0, 0);
      acc1 = __builtin_amdgcn_mfma_f32_16x16x32_bf16(a1, b1, acc1, 0, 0, 0);
    }
  }
  f32x4 acc = acc0 + acc1;

  #pragma unroll
  for (int r = 0; r < 4; ++r){
    int brow = w * 16 + kg * 4 + r;
    glds[brow * 17 + rl] = acc[r];
  }
  __syncthreads();

  int b = tid >> 2, jj = tid & 3;
  int j = blk * 4 + jj;
  int pbase = blk * 16 + jj * 4;
  float gf = glds[b*17 + jj*4 + 0] + biasP[pbase + 0];
  float gi = glds[b*17 + jj*4 + 1] + biasP[pbase + 1];
  float go = glds[b*17 + jj*4 + 2] + biasP[pbase + 2];
  float gc = glds[b*17 + jj*4 + 3] + biasP[pbase + 3];
  float f  = fsigmoid(gf);
  float i_ = fsigmoid(gi);
  float o  = fsigmoid(go);
  float ct = ftanh(gc);
  float c_old = cbuf[b * H_DIM + j];
  float cn = f * c_old + i_ * ct;
  float hn = o * ftanh(cn);
  cbuf[b * H_DIM + j] = cn;
  h_out[b * H_DIM + j] = f2b(hn);
  out[((size_t)b * T_DIM + t) * H_DIM + j] = hn;
}

// ---------------- launch ----------------
extern "C" void kernel_launch(void* const* d_in, const int* in_sizes, int n_in,
                              void* d_out, int out_size, void* d_ws, size_t ws_size,
                              hipStream_t stream){
  (void)in_sizes; (void)n_in; (void)out_size;
  const float* emb = (const float*)d_in[0];
  const float* Wf  = (const float*)d_in[1];
  const float* bfv = (const float*)d_in[2];
  const float* Wi  = (const float*)d_in[3];
  const float* biv = (const float*)d_in[4];
  const float* Wo  = (const float*)d_in[5];
  const float* bov = (const float*)d_in[6];
  const float* Wc  = (const float*)d_in[7];
  const float* bcv = (const float*)d_in[8];
  float* out = (float*)d_out;

  char* ws = (char*)d_ws;
  size_t off = 0;
  auto alloc = [&](size_t bytes) -> void* {
    void* p = ws + off; off += (bytes + 255) & ~(size_t)255; return p;
  };
  unsigned short* WxB   = (unsigned short*)alloc((size_t)G_DIM * 1024 * 2);
  unsigned short* WhB   = (unsigned short*)alloc((size_t)G_DIM * 1024 * 2);
  float*          biasP = (float*)alloc((size_t)G_DIM * 4);
  unsigned short* h0    = (unsigned short*)alloc((size_t)B_DIM * H_DIM * 2);
  unsigned short* h1    = (unsigned short*)alloc((size_t)B_DIM * H_DIM * 2);
  float*          cglob = (float*)alloc((size_t)B_DIM * H_DIM * 4);
  int*            counter = (int*)alloc(256);
  size_t base_end = off;

  // choose largest T-chunk whose embB(bf16) + xg(bf16) buffers fit in d_ws
  int Tc = 0;
  const int cands[6] = {512, 256, 128, 64, 32, 16};
  for (int ci = 0; ci < 6; ++ci){
    size_t need = base_end
                + (size_t)cands[ci] * B_DIM * E_DIM * 2   // embB chunk
                + (size_t)cands[ci] * B_DIM * G_DIM * 2   // xg chunk (bf16)
                + 4096;
    if (ws_size >= need){ Tc = cands[ci]; break; }
  }
  unsigned short* embB = nullptr;
  unsigned short* xgc  = nullptr;
  if (Tc > 0){
    embB = (unsigned short*)alloc((size_t)Tc * B_DIM * E_DIM * 2);
    xgc  = (unsigned short*)alloc((size_t)Tc * B_DIM * G_DIM * 2);
  }

  pack_weights<<<G_DIM, 256, 0, stream>>>(Wf, Wi, Wo, Wc, bfv, biv, bov, bcv, WxB, WhB, biasP);
  zero_state<<<256, 256, 0, stream>>>(h0, h1, cglob, counter);

  if (Tc > 0){
    for (int t0 = 0; t0 < T_DIM; t0 += Tc){
      conv_emb<<<2048, 256, 0, stream>>>(emb + (size_t)t0 * B_DIM * E_DIM, embB,
                                         (size_t)Tc * B_DIM * E_DIM / 4);
      gemm_xg<<<dim3(Tc * B_DIM / 128, G_DIM / 128), 256, 0, stream>>>(embB, WxB, xgc);
      lstm_scan<<<NBLK, 512, 0, stream>>>(WhB, xgc, biasP, h0, h1, cglob, out,
                                          counter, t0, t0 + Tc);
    }
  } else {
    // round-1 proven fallback: fused per-step kernels (no big buffers needed)
    for (int t = 0; t < T_DIM; ++t){
      const unsigned short* hin = (t & 1) ? h1 : h0;
      unsigned short*      hout = (t & 1) ? h0 : h1;
      lstm_step<<<256, 256, 0, stream>>>(
          WhB, WxB, emb + (size_t)t * B_DIM * E_DIM, hin, hout, cglob, biasP, out, t);
    }
  }
}

// Round 6
// 2966.113 us; speedup vs baseline: 3.9941x; 2.1448x over previous
//
#include <hip/hip_runtime.h>
#include <stdint.h>

#define T_DIM 512
#define B_DIM 64
#define E_DIM 1024
#define H_DIM 1024
#define G_DIM 4096   // 4*H, packed as p = j*4 + gate
#define SBLK 256     // scan blocks = CU count (1/CU by LDS, all co-resident)
#define CPB  64      // packed gate-cols per scan block (= 16 hidden units)

typedef short bf16x8 __attribute__((ext_vector_type(8)));
typedef float f32x4 __attribute__((ext_vector_type(4)));

__device__ __forceinline__ unsigned short f2b(float f){
  union{float f; unsigned u;} v; v.f = f;
  unsigned r = (v.u + 0x7FFFu + ((v.u >> 16) & 1u)) >> 16;  // RNE
  return (unsigned short)r;
}
__device__ __forceinline__ float b2f(unsigned short u){
  union{unsigned u; float f;} v; v.u = ((unsigned)u) << 16; return v.f;
}
__device__ __forceinline__ float fsigmoid(float x){
  return 1.f / (1.f + __expf(-x));
}
__device__ __forceinline__ float ftanh(float x){
  return 2.f / (1.f + __expf(-2.f * x)) - 1.f;
}

// 16B coherent load (sc0 sc1: served at device-coherent point, never stale
// per-XCD L2) — r5-proven for cross-XCD h exchange.
template<int OFF>
__device__ __forceinline__ bf16x8 ld_h16(const unsigned short* p){
  bf16x8 r;
  asm volatile("global_load_dwordx4 %0, %1, off offset:%2 sc0 sc1"
               : "=v"(r) : "v"(p), "i"(OFF) : "memory");
  return r;
}
// plain 16B load (xg: producer kernel boundary already made it visible)
__device__ __forceinline__ bf16x8 ld_g16(const unsigned short* p){
  bf16x8 r;
  asm volatile("global_load_dwordx4 %0, %1, off"
               : "=v"(r) : "v"(p) : "memory");
  return r;
}

#define LD8(dst, base, K0) \
  dst[0]=ld_h16<((K0)+0)*64>(base); dst[1]=ld_h16<((K0)+1)*64>(base); \
  dst[2]=ld_h16<((K0)+2)*64>(base); dst[3]=ld_h16<((K0)+3)*64>(base); \
  dst[4]=ld_h16<((K0)+4)*64>(base); dst[5]=ld_h16<((K0)+5)*64>(base); \
  dst[6]=ld_h16<((K0)+6)*64>(base); dst[7]=ld_h16<((K0)+7)*64>(base);

// wait until <=N vmem outstanding; DS_READ (0x100) may hoist past, MFMA/VALU
// may not (rule #18).
#define WAITV(N) \
  asm volatile("s_waitcnt vmcnt(" #N ")" ::: "memory"); \
  __builtin_amdgcn_sched_barrier(0x100);

// 8 kc-steps: per kc read 4 B-frags (4 col-tiles) from LDS, 4 MFMAs into
// 4 independent acc chains.
#define MFMA_GRP(buf, G) \
  { _Pragma("unroll") \
    for (int u = 0; u < 8; ++u){ \
      int kc_ = (G)*8 + u; \
      bf16x8 b0 = *(const bf16x8*)&Wl[((0*32 + kc_)*64 + lane)*8]; \
      bf16x8 b1 = *(const bf16x8*)&Wl[((1*32 + kc_)*64 + lane)*8]; \
      bf16x8 b2 = *(const bf16x8*)&Wl[((2*32 + kc_)*64 + lane)*8]; \
      bf16x8 b3 = *(const bf16x8*)&Wl[((3*32 + kc_)*64 + lane)*8]; \
      acc0 = __builtin_amdgcn_mfma_f32_16x16x32_bf16(buf[u], b0, acc0, 0,0,0); \
      acc1 = __builtin_amdgcn_mfma_f32_16x16x32_bf16(buf[u], b1, acc1, 0,0,0); \
      acc2 = __builtin_amdgcn_mfma_f32_16x16x32_bf16(buf[u], b2, acc2, 0,0,0); \
      acc3 = __builtin_amdgcn_mfma_f32_16x16x32_bf16(buf[u], b3, acc3, 0,0,0); \
    } }

// ---------------- prep kernels ----------------

__global__ void pack_weights(const float* __restrict__ Wf, const float* __restrict__ Wi,
                             const float* __restrict__ Wo, const float* __restrict__ Wc,
                             const float* __restrict__ bfv, const float* __restrict__ biv,
                             const float* __restrict__ bov, const float* __restrict__ bcv,
                             unsigned short* __restrict__ WxB, unsigned short* __restrict__ WhB,
                             float* __restrict__ biasP){
  int p = blockIdx.x;            // 0..4095
  int j = p >> 2, g = p & 3;
  const float* W    = (g==0)?Wf:(g==1)?Wi:(g==2)?Wo:Wc;
  const float* bsrc = (g==0)?bfv:(g==1)?biv:(g==2)?bov:bcv;
  const float* wrow = W + (size_t)j * 2048;
  int t = threadIdx.x;           // 256 threads, 4 k each
  float4 x = *(const float4*)(wrow + 4*t);
  float4 h = *(const float4*)(wrow + 1024 + 4*t);
  ushort4 xo = make_ushort4(f2b(x.x), f2b(x.y), f2b(x.z), f2b(x.w));
  ushort4 ho = make_ushort4(f2b(h.x), f2b(h.y), f2b(h.z), f2b(h.w));
  *(ushort4*)&WxB[(size_t)p*1024 + 4*t] = xo;
  *(ushort4*)&WhB[(size_t)p*1024 + 4*t] = ho;
  if (t == 0) biasP[p] = bsrc[j];
}

__global__ void conv_emb(const float* __restrict__ emb, unsigned short* __restrict__ embB,
                         size_t n4){
  for (size_t i = (size_t)blockIdx.x * blockDim.x + threadIdx.x; i < n4;
       i += (size_t)gridDim.x * blockDim.x){
    float4 v = ((const float4*)emb)[i];
    ((ushort4*)embB)[i] = make_ushort4(f2b(v.x), f2b(v.y), f2b(v.z), f2b(v.w));
  }
}

__global__ void zero_state(unsigned short* __restrict__ h0, unsigned short* __restrict__ h1,
                           float* __restrict__ c, int* __restrict__ flags){
  int i = blockIdx.x * blockDim.x + threadIdx.x;  // 65536 threads exactly
  h0[i] = 0; h1[i] = 0; c[i] = 0.f;
  if (i < SBLK * 16) flags[i] = 0;
}

// ---------------- big GEMM: xg_chunk = embB @ WxB^T (bf16 out) ----------------
__launch_bounds__(256)
__global__ void gemm_xg(const unsigned short* __restrict__ A,
                        const unsigned short* __restrict__ B,
                        unsigned short* __restrict__ C){
  __shared__ unsigned short Al[128*32];
  __shared__ unsigned short Bl[128*32];
  int m0 = blockIdx.x * 128, n0 = blockIdx.y * 128;
  int tid = threadIdx.x, lane = tid & 63, wid = tid >> 6;
  int mblk = (wid >> 1) * 64, nblk = (wid & 1) * 64;
  int rl = lane & 15, kg = lane >> 4;
  f32x4 acc[4][4] = {};

  for (int kk = 0; kk < 1024; kk += 32){
    {
      int c0 = tid, c1 = tid + 256;
      int r = c0 >> 2, g = c0 & 3, s = g ^ ((r >> 1) & 3);
      *(uint4*)&Al[r*32 + s*8] = *(const uint4*)&A[(size_t)(m0 + r)*1024 + kk + g*8];
      *(uint4*)&Bl[r*32 + s*8] = *(const uint4*)&B[(size_t)(n0 + r)*1024 + kk + g*8];
      r = c1 >> 2; g = c1 & 3; s = g ^ ((r >> 1) & 3);
      *(uint4*)&Al[r*32 + s*8] = *(const uint4*)&A[(size_t)(m0 + r)*1024 + kk + g*8];
      *(uint4*)&Bl[r*32 + s*8] = *(const uint4*)&B[(size_t)(n0 + r)*1024 + kk + g*8];
    }
    __syncthreads();
    bf16x8 a[4], b[4];
    #pragma unroll
    for (int mf = 0; mf < 4; ++mf){
      int r = mblk + mf*16 + rl;
      a[mf] = *(const bf16x8*)&Al[r*32 + (kg ^ ((r >> 1) & 3))*8];
    }
    #pragma unroll
    for (int nf = 0; nf < 4; ++nf){
      int r = nblk + nf*16 + rl;
      b[nf] = *(const bf16x8*)&Bl[r*32 + (kg ^ ((r >> 1) & 3))*8];
    }
    #pragma unroll
    for (int mf = 0; mf < 4; ++mf)
      #pragma unroll
      for (int nf = 0; nf < 4; ++nf)
        acc[mf][nf] = __builtin_amdgcn_mfma_f32_16x16x32_bf16(a[mf], b[nf], acc[mf][nf], 0, 0, 0);
    __syncthreads();
  }

  // C/D layout (m89-verified): col = lane&15, row = (lane>>4)*4 + reg
  int rq = kg * 4;
  #pragma unroll
  for (int mf = 0; mf < 4; ++mf)
    #pragma unroll
    for (int nf = 0; nf < 4; ++nf){
      int col = n0 + nblk + nf*16 + rl;
      #pragma unroll
      for (int r = 0; r < 4; ++r){
        int row = m0 + mblk + mf*16 + rq + r;
        C[(size_t)row * G_DIM + col] = f2b(acc[mf][nf][r]);
      }
    }
}

// ---------------- persistent recurrent scan ----------------
// 256 blocks x 64 threads (1 wave), 1 block/CU (132 KB LDS), all 256 CUs.
// Block = (cs = blk>>2: 16 hidden units / 64 packed cols; rq = blk&3: 16
// batch rows). Wh slice in LDS fragment-major. h read 1x (only own rows)
// via sc0/sc1 coherent 16B loads, 4-buffer counted-vmcnt pipeline. c in
// registers. Barrier: 4 INDEPENDENT per-rq flag barriers (blocks only
// consume h rows produced by same-rq blocks) — no RMW, no hot line.
__launch_bounds__(64, 1)
__global__ void lstm_scan(const unsigned short* __restrict__ WhB,
                          const unsigned short* __restrict__ xgc,  // bf16 [t1-t0][B][G]
                          const float* __restrict__ biasP,
                          unsigned short* __restrict__ hb0,
                          unsigned short* __restrict__ hb1,
                          float* __restrict__ cglob,
                          float* __restrict__ out,
                          int* __restrict__ flags,
                          int t0, int t1){
  __shared__ unsigned short Wl[4*32*64*8];   // 128 KB frag-major [ct][kc][lane][8]
  __shared__ float gl[16][68];               // 4.35 KB gate staging (+pad)

  const int tid = threadIdx.x;               // 0..63 (one wave)
  const int blk = blockIdx.x;
  const int cs = blk >> 2, rq = blk & 3;
  const int lane = tid;
  const int rl = lane & 15, kg = lane >> 4;

  // One-time: stage Wh fragments (A/B share the same (lane,elem)->k map)
  for (int idx = tid; idx < 4*32*64; idx += 64){
    int ct = idx >> 11, kc = (idx >> 6) & 31, l = idx & 63;
    int col = cs*CPB + ct*16 + (l & 15);
    int k   = kc*32 + (l >> 4)*8;
    *(bf16x8*)&Wl[idx*8] = *(const bf16x8*)&WhB[(size_t)col*1024 + k];
  }

  // elementwise mapping: thread -> (local batch row bb, 16 packed cols at cb)
  const int bb = tid >> 2, q = tid & 3, cb = q * 16;
  const int rowg = rq*16 + bb;               // global batch row
  const int jb = cs*16 + q*4;                // 4 hidden units owned
  f32x4 bias[4];
  #pragma unroll
  for (int p = 0; p < 4; ++p)
    bias[p] = *(const f32x4*)&biasP[cs*CPB + cb + p*4];
  f32x4 cv = *(const f32x4*)&cglob[(size_t)rowg*H_DIM + jb];

  const int* fpoll = &flags[(4*lane + rq) * 16];  // my rq-group's 64 flags

  __syncthreads();
  asm volatile("s_waitcnt vmcnt(0)" ::: "memory");  // clean vmcnt for counted loop

  for (int t = t0; t < t1; ++t){
    const unsigned short* hin = (t & 1) ? hb1 : hb0;
    unsigned short* hout = (t & 1) ? hb0 : hb1;

    // issue xg (oldest) + all 32 A-frag loads (rows rq*16..+16, K=1024)
    const unsigned short* xgp = xgc + ((size_t)(t - t0)*B_DIM + rowg)*G_DIM + cs*CPB + cb;
    const unsigned short* ap  = hin + (size_t)(rq*16 + rl)*1024 + kg*8;
    bf16x8 xr0 = ld_g16(xgp);
    bf16x8 xr1 = ld_g16(xgp + 8);
    bf16x8 aA[8], aB[8], aC[8], aD[8];
    LD8(aA, ap, 0);  LD8(aB, ap, 8);  LD8(aC, ap, 16);  LD8(aD, ap, 24);

    f32x4 acc0 = {}, acc1 = {}, acc2 = {}, acc3 = {};
    WAITV(24);   // xr0,xr1 + aA complete
    MFMA_GRP(aA, 0);
    WAITV(16);   // aB complete
    MFMA_GRP(aB, 1);
    WAITV(8);    // aC complete
    MFMA_GRP(aC, 2);
    WAITV(0);    // aD complete
    MFMA_GRP(aD, 3);

    // scatter to LDS; C/D: col=lane&15, row=(lane>>4)*4+reg (m89-verified)
    {
      int r0 = kg * 4;
      #pragma unroll
      for (int r = 0; r < 4; ++r){
        gl[r0 + r][ 0 + rl] = acc0[r];
        gl[r0 + r][16 + rl] = acc1[r];
        gl[r0 + r][32 + rl] = acc2[r];
        gl[r0 + r][48 + rl] = acc3[r];
      }
    }
    __syncthreads();

    // gates: thread handles 4 hidden units (16 packed cols at cb)
    union { ushort4 s; unsigned long long qq; } hu;
    f32x4 ov;
    {
      f32x4 g0, g1, g2, g3;
      #pragma unroll
      for (int e = 0; e < 4; ++e){
        g0[e] = gl[bb][cb +  0 + e] + b2f(xr0[e])     + bias[0][e];
        g1[e] = gl[bb][cb +  4 + e] + b2f(xr0[4 + e]) + bias[1][e];
        g2[e] = gl[bb][cb +  8 + e] + b2f(xr1[e])     + bias[2][e];
        g3[e] = gl[bb][cb + 12 + e] + b2f(xr1[4 + e]) + bias[3][e];
      }
      float f, i_, o, ct_, hn;
      f = fsigmoid(g0[0]); i_ = fsigmoid(g0[1]); o = fsigmoid(g0[2]); ct_ = ftanh(g0[3]);
      cv[0] = f*cv[0] + i_*ct_; hn = o*ftanh(cv[0]); hu.s.x = f2b(hn); ov[0] = hn;
      f = fsigmoid(g1[0]); i_ = fsigmoid(g1[1]); o = fsigmoid(g1[2]); ct_ = ftanh(g1[3]);
      cv[1] = f*cv[1] + i_*ct_; hn = o*ftanh(cv[1]); hu.s.y = f2b(hn); ov[1] = hn;
      f = fsigmoid(g2[0]); i_ = fsigmoid(g2[1]); o = fsigmoid(g2[2]); ct_ = ftanh(g2[3]);
      cv[2] = f*cv[2] + i_*ct_; hn = o*ftanh(cv[2]); hu.s.z = f2b(hn); ov[2] = hn;
      f = fsigmoid(g3[0]); i_ = fsigmoid(g3[1]); o = fsigmoid(g3[2]); ct_ = ftanh(g3[3]);
      cv[3] = f*cv[3] + i_*ct_; hn = o*ftanh(cv[3]); hu.s.w = f2b(hn); ov[3] = hn;
    }
    // h store at coherent point so same-rq blocks on all XCDs see it
    __hip_atomic_store((unsigned long long*)&hout[(size_t)rowg*H_DIM + jb], hu.qq,
                       __ATOMIC_RELAXED, __HIP_MEMORY_SCOPE_AGENT);
    *(f32x4*)&out[((size_t)rowg*T_DIM + t)*H_DIM + jb] = ov;

    // per-rq-group flag barrier (skip after final step):
    // drain own stores -> signal own flag -> each lane spins on one member.
    if (t + 1 < t1){
      asm volatile("s_waitcnt vmcnt(0)" ::: "memory");
      __syncthreads();
      if (tid == 0)
        __hip_atomic_store(&flags[blk * 16], t + 1,
                           __ATOMIC_RELAXED, __HIP_MEMORY_SCOPE_AGENT);
      {
        const int target = t + 1;
        while (__hip_atomic_load(fpoll, __ATOMIC_RELAXED, __HIP_MEMORY_SCOPE_AGENT) < target)
          __builtin_amdgcn_s_sleep(1);
      }
      __syncthreads();
      asm volatile("" ::: "memory");  // keep next-step loads below the spin
    }
  }

  *(f32x4*)&cglob[(size_t)rowg*H_DIM + jb] = cv;
}

// ---------------- round-1 proven fallback: per-step launched kernel ----------------
__device__ __forceinline__ bf16x8 cvt_f8(const float* p){
  float4 u = *(const float4*)p;
  float4 v = *(const float4*)(p + 4);
  bf16x8 r;
  r[0] = (short)f2b(u.x); r[1] = (short)f2b(u.y); r[2] = (short)f2b(u.z); r[3] = (short)f2b(u.w);
  r[4] = (short)f2b(v.x); r[5] = (short)f2b(v.y); r[6] = (short)f2b(v.z); r[7] = (short)f2b(v.w);
  return r;
}

__launch_bounds__(256)
__global__ void lstm_step(const unsigned short* __restrict__ WhB,
                          const unsigned short* __restrict__ WxB,
                          const float* __restrict__ emb_t,
                          const unsigned short* __restrict__ h_in,
                          unsigned short* __restrict__ h_out,
                          float* __restrict__ cbuf,
                          const float* __restrict__ biasP,
                          float* __restrict__ out, int t){
  __shared__ float glds[64 * 17];
  int tid = threadIdx.x, lane = tid & 63, w = tid >> 6;
  int blk = blockIdx.x;
  int rl = lane & 15, kg = lane >> 4;
  int arow = w * 16 + rl;
  int pcol = blk * 16 + rl;

  f32x4 acc0 = {}, acc1 = {};
  const unsigned short* hrow = h_in + (size_t)arow * 1024 + kg * 8;
  const unsigned short* wrow = WhB + (size_t)pcol * 1024 + kg * 8;
  #pragma unroll 4
  for (int kk = 0; kk < 1024; kk += 64){
    bf16x8 a0 = *(const bf16x8*)(hrow + kk);
    bf16x8 b0 = *(const bf16x8*)(wrow + kk);
    bf16x8 a1 = *(const bf16x8*)(hrow + kk + 32);
    bf16x8 b1 = *(const bf16x8*)(wrow + kk + 32);
    acc0 = __builtin_amdgcn_mfma_f32_16x16x32_bf16(a0, b0, acc0, 0, 0, 0);
    acc1 = __builtin_amdgcn_mfma_f32_16x16x32_bf16(a1, b1, acc1, 0, 0, 0);
  }
  {
    const float* xrow = emb_t + (size_t)arow * 1024 + kg * 8;
    const unsigned short* wxrow = WxB + (size_t)pcol * 1024 + kg * 8;
    #pragma unroll 4
    for (int kk = 0; kk < 1024; kk += 64){
      bf16x8 a0 = cvt_f8(xrow + kk);
      bf16x8 b0 = *(const bf16x8*)(wxrow + kk);
      bf16x8 a1 = cvt_f8(xrow + kk + 32);
      bf16x8 b1 = *(const bf16x8*)(wxrow + kk + 32);
      acc0 = __builtin_amdgcn_mfma_f32_16x16x32_bf16(a0, b0, acc0, 0, 0, 0);
      acc1 = __builtin_amdgcn_mfma_f32_16x16x32_bf16(a1, b1, acc1, 0, 0, 0);
    }
  }
  f32x4 acc = acc0 + acc1;

  #pragma unroll
  for (int r = 0; r < 4; ++r){
    int brow = w * 16 + kg * 4 + r;
    glds[brow * 17 + rl] = acc[r];
  }
  __syncthreads();

  int b = tid >> 2, jj = tid & 3;
  int j = blk * 4 + jj;
  int pbase = blk * 16 + jj * 4;
  float gf = glds[b*17 + jj*4 + 0] + biasP[pbase + 0];
  float gi = glds[b*17 + jj*4 + 1] + biasP[pbase + 1];
  float go = glds[b*17 + jj*4 + 2] + biasP[pbase + 2];
  float gc = glds[b*17 + jj*4 + 3] + biasP[pbase + 3];
  float f  = fsigmoid(gf);
  float i_ = fsigmoid(gi);
  float o  = fsigmoid(go);
  float ct = ftanh(gc);
  float c_old = cbuf[b * H_DIM + j];
  float cn = f * c_old + i_ * ct;
  float hn = o * ftanh(cn);
  cbuf[b * H_DIM + j] = cn;
  h_out[b * H_DIM + j] = f2b(hn);
  out[((size_t)b * T_DIM + t) * H_DIM + j] = hn;
}

// ---------------- launch ----------------
extern "C" void kernel_launch(void* const* d_in, const int* in_sizes, int n_in,
                              void* d_out, int out_size, void* d_ws, size_t ws_size,
                              hipStream_t stream){
  (void)in_sizes; (void)n_in; (void)out_size;
  const float* emb = (const float*)d_in[0];
  const float* Wf  = (const float*)d_in[1];
  const float* bfv = (const float*)d_in[2];
  const float* Wi  = (const float*)d_in[3];
  const float* biv = (const float*)d_in[4];
  const float* Wo  = (const float*)d_in[5];
  const float* bov = (const float*)d_in[6];
  const float* Wc  = (const float*)d_in[7];
  const float* bcv = (const float*)d_in[8];
  float* out = (float*)d_out;

  char* ws = (char*)d_ws;
  size_t off = 0;
  auto alloc = [&](size_t bytes) -> void* {
    void* p = ws + off; off += (bytes + 255) & ~(size_t)255; return p;
  };
  unsigned short* WxB   = (unsigned short*)alloc((size_t)G_DIM * 1024 * 2);
  unsigned short* WhB   = (unsigned short*)alloc((size_t)G_DIM * 1024 * 2);
  float*          biasP = (float*)alloc((size_t)G_DIM * 4);
  unsigned short* h0    = (unsigned short*)alloc((size_t)B_DIM * H_DIM * 2);
  unsigned short* h1    = (unsigned short*)alloc((size_t)B_DIM * H_DIM * 2);
  float*          cglob = (float*)alloc((size_t)B_DIM * H_DIM * 4);
  int*            flags = (int*)alloc((size_t)SBLK * 16 * 4);
  size_t base_end = off;

  // choose largest T-chunk whose embB(bf16) + xg(bf16) buffers fit in d_ws
  int Tc = 0;
  const int cands[6] = {512, 256, 128, 64, 32, 16};
  for (int ci = 0; ci < 6; ++ci){
    size_t need = base_end
                + (size_t)cands[ci] * B_DIM * E_DIM * 2   // embB chunk
                + (size_t)cands[ci] * B_DIM * G_DIM * 2   // xg chunk (bf16)
                + 4096;
    if (ws_size >= need){ Tc = cands[ci]; break; }
  }
  unsigned short* embB = nullptr;
  unsigned short* xgc  = nullptr;
  if (Tc > 0){
    embB = (unsigned short*)alloc((size_t)Tc * B_DIM * E_DIM * 2);
    xgc  = (unsigned short*)alloc((size_t)Tc * B_DIM * G_DIM * 2);
  }

  pack_weights<<<G_DIM, 256, 0, stream>>>(Wf, Wi, Wo, Wc, bfv, biv, bov, bcv, WxB, WhB, biasP);
  zero_state<<<256, 256, 0, stream>>>(h0, h1, cglob, flags);

  if (Tc > 0){
    for (int t0 = 0; t0 < T_DIM; t0 += Tc){
      conv_emb<<<2048, 256, 0, stream>>>(emb + (size_t)t0 * B_DIM * E_DIM, embB,
                                         (size_t)Tc * B_DIM * E_DIM / 4);
      gemm_xg<<<dim3(Tc * B_DIM / 128, G_DIM / 128), 256, 0, stream>>>(embB, WxB, xgc);
      lstm_scan<<<SBLK, 64, 0, stream>>>(WhB, xgc, biasP, h0, h1, cglob, out,
                                         flags, t0, t0 + Tc);
    }
  } else {
    // round-1 proven fallback: fused per-step kernels (no big buffers needed)
    for (int t = 0; t < T_DIM; ++t){
      const unsigned short* hin = (t & 1) ? h1 : h0;
      unsigned short*      hout = (t & 1) ? h0 : h1;
      lstm_step<<<256, 256, 0, stream>>>(
          WhB, WxB, emb + (size_t)t * B_DIM * E_DIM, hin, hout, cglob, biasP, out, t);
    }
  }
}